// Round 8
// baseline (1076.925 us; speedup 1.0000x reference)
//
#include <hip/hip_runtime.h>
#include <math.h>

#define C_   128
#define HU_  128
#define WU_  192
#define HD_  64
#define WD_  96

typedef unsigned short u16;
typedef __attribute__((ext_vector_type(8))) short s8v;   // 8 bf16 = 4 VGPRs
typedef __attribute__((ext_vector_type(4))) float f4v;   // MFMA C/D

// ---- workspace layout (u16 units) ----
#define OFF_Q   0        // 2 layers x 16384
#define OFF_K   32768
#define OFF_V   65536
#define OFF_O   98304
#define OFF_F1  131072   // 2 layers x 65536
#define OFF_F2  262144
#define OFF_XC  393216   // 49152 (out1 Wa+Wc, 128x384)
#define OFF_CC  442368   // 49152 (out1 Wb-Wc, 128x384)
#define OFF_NRM 491520   // normalized ctx bf16: (B,HD,WD,C) = 1572864 u16

#define SLOT 2176        // u16 per LDS tile slot (16 rows x 136)

__device__ __forceinline__ u16 f2bf(float f) {
    unsigned u = __float_as_uint(f);
    unsigned r = (u + 0x7FFFu + ((u >> 16) & 1u)) >> 16;   // RNE
    return (u16)r;
}
__device__ __forceinline__ float bfu(u16 h) { return __uint_as_float(((unsigned)h) << 16); }

__device__ __forceinline__ float gelu_tanh(float x) {
    float u = 1.5957691216057308f * (x + 0.044715f * x * x * x);
    float e = __expf(u);
    float th = 1.0f - 2.0f / (1.0f + e);
    return 0.5f * x * (1.0f + th);
}
__device__ __forceinline__ float fast_erf(float x) {
    float z = fabsf(x);
    float t = 1.0f / (1.0f + 0.3275911f * z);
    float p = t * (0.254829592f + t * (-0.284496736f + t * (1.421413741f +
              t * (-1.453152027f + t * 1.061405429f))));
    float r = 1.0f - p * __expf(-z * z);
    return copysignf(r, x);
}
__device__ __forceinline__ float gelu_erf(float x) {
    return 0.5f * x * (1.0f + fast_erf(x * 0.7071067811865476f));
}

// ---------------- prologue 1: all weight swizzles (+ out1 folding) ----------------
__global__ __launch_bounds__(256) void swz_all(
    const float* __restrict__ q_w, const float* __restrict__ k_w,
    const float* __restrict__ v_w, const float* __restrict__ o_w,
    const float* __restrict__ f1w, const float* __restrict__ f2w,
    const float* __restrict__ o1w, u16* __restrict__ ws)
{
    int tid = blockIdx.x * 256 + threadIdx.x;
    int f = tid >> 6, lane = tid & 63;
    int rq = 8 * (lane >> 4), cq = lane & 15;
    const float* src; const float* src2 = nullptr; float sgn = 1.f;
    int NT, N, dstoff, lf;
    if (f < 64)       { src = q_w;  NT = 8;  N = 128; dstoff = OFF_Q;  lf = f; }
    else if (f < 128) { src = k_w;  NT = 8;  N = 128; dstoff = OFF_K;  lf = f - 64; }
    else if (f < 192) { src = v_w;  NT = 8;  N = 128; dstoff = OFF_V;  lf = f - 128; }
    else if (f < 256) { src = o_w;  NT = 8;  N = 128; dstoff = OFF_O;  lf = f - 192; }
    else if (f < 512) { src = f1w;  NT = 32; N = 512; dstoff = OFF_F1; lf = f - 256; }
    else if (f < 768) { src = f2w;  NT = 8;  N = 128; dstoff = OFF_F2; lf = f - 512; }
    else if (f < 864) { src = o1w;             src2 = o1w + 256 * 384; sgn =  1.f;
                        NT = 24; N = 384; dstoff = OFF_XC; lf = f - 768; }
    else              { src = o1w + 128 * 384; src2 = o1w + 256 * 384; sgn = -1.f;
                        NT = 24; N = 384; dstoff = OFF_CC; lf = f - 864; }
    int kt = lf / NT, nt = lf - kt * NT;
    int row0 = kt * 32 + rq, col = nt * 16 + cq;
    s8v o;
#pragma unroll
    for (int j = 0; j < 8; ++j) {
        float v = src[(size_t)(row0 + j) * N + col];
        if (src2) v += sgn * src2[(size_t)(row0 + j) * N + col];
        o[j] = (short)f2bf(v);
    }
    *(s8v*)(ws + dstoff + (size_t)lf * 512 + (size_t)lane * 8) = o;
}

// ---------------- prologue 2: per-down-pixel LN of feat_map (eps 1e-5) ----------------
__global__ __launch_bounds__(256) void norm_kernel(const float* __restrict__ fm,
                                                   u16* __restrict__ dst) {
    int row = blockIdx.x;          // b*HD + y
    int b = row >> 6, y = row & 63;
    __shared__ float tile[128 * 97];
    __shared__ float smean[96], srst[96];
    for (int idx = threadIdx.x; idx < 128 * 96; idx += 256) {
        int c = idx / 96, w = idx - c * 96;
        tile[c * 97 + w] = fm[(((size_t)b * 128 + c) * 64 + y) * 96 + w];
    }
    __syncthreads();
    if (threadIdx.x < 96) {
        int w = threadIdx.x;
        float s = 0.f, ss = 0.f;
        for (int c = 0; c < 128; ++c) { float v = tile[c * 97 + w]; s += v; ss += v * v; }
        float mn = s * (1.f / 128.f);
        smean[w] = mn;
        srst[w]  = rsqrtf(ss * (1.f / 128.f) - mn * mn + 1e-5f);
    }
    __syncthreads();
    for (int idx = threadIdx.x; idx < 96 * 16; idx += 256) {
        int w = idx >> 4, cg = idx & 15;
        float mn = smean[w], iv = srst[w];
        s8v o;
#pragma unroll
        for (int j = 0; j < 8; ++j)
            o[j] = (short)f2bf((tile[(8 * cg + j) * 97 + w] - mn) * iv);
        *(s8v*)(dst + ((size_t)row * 96 + w) * 128 + 8 * cg) = o;
    }
}

// ---------------- main fused kernel: 2 waves / block, 16 pixels / block ----------------
// Wave wv handles N-halves: nt_g = 4*wv..4*wv+3 (q/v/o/fc2), heads 2wv..2wv+1 (k),
// nt_g = 16wv.. (fc1), ntc chunks 2wv..2wv+1 (head). Shared LDS tiles, s_red for LN.
__global__ __launch_bounds__(128, 3) void fused_kernel(
    const u16*  __restrict__ nrmb, const float* __restrict__ fmu,
    const u16*  __restrict__ wsb,
    const float* __restrict__ ctx_g, const float* __restrict__ ctx_b,
    const float* __restrict__ qb, const float* __restrict__ kb,
    const float* __restrict__ vb, const float* __restrict__ ob,
    const float* __restrict__ f1b, const float* __restrict__ f2b,
    const float* __restrict__ o1b, const float* __restrict__ o2w,
    const float* __restrict__ o2b,
    float* __restrict__ out)
{
    const int tid  = threadIdx.x;
    const int wv   = tid >> 6;
    const int lane = tid & 63;
    const int cidx = lane & 15, quad = lane >> 4;
    const int n0 = blockIdx.x * 16;
    const int b  = n0 / (HU_ * WU_);
    const int rem = n0 - b * (HU_ * WU_);
    const int hu  = rem / WU_;
    const int wu0 = rem - hu * WU_;

    __shared__ u16 arena[5 * SLOT];     // 21760 B: slot0 = xn/q/oT/hn/xf, slots1-4 = cn/cf; sH overlays 0-3
    __shared__ float s_at[272];
    __shared__ float s_red[128];
    u16* sH = arena;                    // fc1 acts, stride 520

    // residual x: wave wv owns channels 16*(4wv+ntl)+cidx, rows p = 4*quad+r
    float xacc[4][4];
#pragma unroll
    for (int ntl = 0; ntl < 4; ++ntl) {
        int ch = 16 * (4 * wv + ntl) + cidx;
        float4 v = *(const float4*)(fmu + ((size_t)(b * C_ + ch) * HU_ + hu) * WU_ + wu0 + 4 * quad);
        xacc[ntl][0] = v.x; xacc[ntl][1] = v.y; xacc[ntl][2] = v.z; xacc[ntl][3] = v.w;
    }

    const float slopes[4] = {0.451801007f, 0.204124145f, 0.092223264f, 0.041666668f};
    const int ry0 = min(hu >> 1, HD_ - 1);
    const int ry1 = min((hu >> 1) + 1, HD_ - 1);
    const float dyv0 = -(float)abs(hu - 2 * ry0);
    const float dyv1 = -(float)abs(hu - 2 * ry1);

    // ctx row base for the two tiles this wave builds (mtg = 2wv+i); tile row cidx = (p,k2)
    const int k2l = cidx & 3;
    const int ryl = (k2l >> 1) ? ry1 : ry0;
    int cbase[2];
#pragma unroll
    for (int i = 0; i < 2; ++i) {
        int mtg = 2 * wv + i;
        int p = 4 * mtg + (cidx >> 2);
        int rxv = min(((wu0 + p) >> 1) + (k2l & 1), WD_ - 1);
        cbase[i] = ((b * HD_ + ryl) * WD_ + rxv) * 128;
    }

#pragma unroll 1
    for (int ly = 0; ly < 2; ++ly) {
        const u16* Wq = wsb + OFF_Q  + ly * 16384;
        const u16* Wk = wsb + OFF_K  + ly * 16384;
        const u16* Wv = wsb + OFF_V  + ly * 16384;
        const u16* Wo = wsb + OFF_O  + ly * 16384;
        const u16* W1 = wsb + OFF_F1 + ly * 65536;
        const u16* W2 = wsb + OFF_F2 + ly * 65536;
        const float* gv = ctx_g + ly * C_;
        const float* bv = ctx_b + ly * C_;

        // ---- xn = LN(x,1e-6), cross-wave stats -> slot0 ----
        {
            float s[4], ss[4];
#pragma unroll
            for (int r = 0; r < 4; ++r) {
                s[r] = 0.f; ss[r] = 0.f;
#pragma unroll
                for (int ntl = 0; ntl < 4; ++ntl) { float v = xacc[ntl][r]; s[r] += v; ss[r] += v * v; }
#pragma unroll
                for (int m = 1; m <= 8; m <<= 1) { s[r] += __shfl_xor(s[r], m, 64); ss[r] += __shfl_xor(ss[r], m, 64); }
            }
            if (cidx == 0) {
#pragma unroll
                for (int r = 0; r < 4; ++r) {
                    int p = 4 * quad + r;
                    s_red[p * 2 + wv] = s[r];
                    s_red[64 + p * 2 + wv] = ss[r];
                }
            }
            __syncthreads();
            float mo[4], io[4];
#pragma unroll
            for (int r = 0; r < 4; ++r) {
                int p = 4 * quad + r;
                float st  = s_red[p * 2] + s_red[p * 2 + 1];
                float sst = s_red[64 + p * 2] + s_red[64 + p * 2 + 1];
                float mn = st * (1.f / 128.f);
                mo[r] = mn; io[r] = rsqrtf(sst * (1.f / 128.f) - mn * mn + 1e-6f);
            }
#pragma unroll
            for (int ntl = 0; ntl < 4; ++ntl)
#pragma unroll
                for (int r = 0; r < 4; ++r)
                    arena[(4 * quad + r) * 136 + 16 * (4 * wv + ntl) + cidx] =
                        f2bf((xacc[ntl][r] - mo[r]) * io[r]);
        }

        // ---- build cn tiles (this wave: mtg = 2wv, 2wv+1) -> slots 1-4 ----
#pragma unroll
        for (int i = 0; i < 2; ++i) {
            int mtg = 2 * wv + i;
            const u16* csrc = nrmb + cbase[i] + 32 * quad;
            u16* drow = arena + (1 + mtg) * SLOT + cidx * 136 + 32 * quad;
#pragma unroll
            for (int t = 0; t < 4; ++t) {
                s8v raw = *(const s8v*)(csrc + 8 * t);
                float4 g0 = *(const float4*)&gv[32 * quad + 8 * t];
                float4 g1 = *(const float4*)&gv[32 * quad + 8 * t + 4];
                float4 b0 = *(const float4*)&bv[32 * quad + 8 * t];
                float4 b1 = *(const float4*)&bv[32 * quad + 8 * t + 4];
                s8v o;
                o[0] = (short)f2bf(fmaf(bfu((u16)raw[0]), g0.x, b0.x));
                o[1] = (short)f2bf(fmaf(bfu((u16)raw[1]), g0.y, b0.y));
                o[2] = (short)f2bf(fmaf(bfu((u16)raw[2]), g0.z, b0.z));
                o[3] = (short)f2bf(fmaf(bfu((u16)raw[3]), g0.w, b0.w));
                o[4] = (short)f2bf(fmaf(bfu((u16)raw[4]), g1.x, b1.x));
                o[5] = (short)f2bf(fmaf(bfu((u16)raw[5]), g1.y, b1.y));
                o[6] = (short)f2bf(fmaf(bfu((u16)raw[6]), g1.z, b1.z));
                o[7] = (short)f2bf(fmaf(bfu((u16)raw[7]), g1.w, b1.w));
                *(s8v*)(drow + 8 * t) = o;
            }
        }
        __syncthreads();

        // ---- q: read xn frags, barrier, GEMM (nt half), overwrite slot0 with q bf16 ----
        s8v a_xn[4];
#pragma unroll
        for (int kt = 0; kt < 4; ++kt)
            a_xn[kt] = *(const s8v*)(arena + cidx * 136 + kt * 32 + 8 * quad);
        __syncthreads();
        {
            f4v qa[4];
#pragma unroll
            for (int ntl = 0; ntl < 4; ++ntl) {
                float bvv = qb[ly * C_ + 16 * (4 * wv + ntl) + cidx];
                f4v t = {bvv, bvv, bvv, bvv}; qa[ntl] = t;
            }
#pragma unroll
            for (int kt = 0; kt < 4; ++kt)
#pragma unroll
                for (int ntl = 0; ntl < 4; ++ntl) {
                    s8v w = *(const s8v*)(Wq + ((size_t)((kt * 8 + 4 * wv + ntl) * 64 + lane)) * 8);
                    qa[ntl] = __builtin_amdgcn_mfma_f32_16x16x32_bf16(a_xn[kt], w, qa[ntl], 0, 0, 0);
                }
#pragma unroll
            for (int ntl = 0; ntl < 4; ++ntl)
#pragma unroll
                for (int r = 0; r < 4; ++r)
                    arena[(4 * quad + r) * 136 + 16 * (4 * wv + ntl) + cidx] = f2bf(qa[ntl][r]);
        }
        __syncthreads();

        // ---- k GEMM (this wave: heads 2wv, 2wv+1) + fused raw scores -> s_at ----
#pragma unroll 1
        for (int h_l = 0; h_l < 2; ++h_l) {
            int h = 2 * wv + h_l;
            f4v ka[2][4];
#pragma unroll
            for (int ntp = 0; ntp < 2; ++ntp) {
                float kbb = kb[ly * C_ + 16 * (2 * h + ntp) + cidx];
#pragma unroll
                for (int mt = 0; mt < 4; ++mt) { f4v t = {kbb, kbb, kbb, kbb}; ka[ntp][mt] = t; }
            }
#pragma unroll
            for (int kt = 0; kt < 4; ++kt) {
                s8v acn[4];
#pragma unroll
                for (int mt = 0; mt < 4; ++mt)
                    acn[mt] = *(const s8v*)(arena + (1 + mt) * SLOT + cidx * 136 + kt * 32 + 8 * quad);
#pragma unroll
                for (int ntp = 0; ntp < 2; ++ntp) {
                    s8v w = *(const s8v*)(Wk + ((size_t)((kt * 8 + 2 * h + ntp) * 64 + lane)) * 8);
#pragma unroll
                    for (int mt = 0; mt < 4; ++mt)
                        ka[ntp][mt] = __builtin_amdgcn_mfma_f32_16x16x32_bf16(acn[mt], w, ka[ntp][mt], 0, 0, 0);
                }
            }
            float part[4][4];
#pragma unroll
            for (int mt = 0; mt < 4; ++mt)
#pragma unroll
                for (int r = 0; r < 4; ++r) part[mt][r] = 0.f;
#pragma unroll
            for (int ntp = 0; ntp < 2; ++ntp)
#pragma unroll
                for (int mt = 0; mt < 4; ++mt) {
                    float qv = bfu(arena[(4 * mt + quad) * 136 + 16 * (2 * h + ntp) + cidx]);
#pragma unroll
                    for (int r = 0; r < 4; ++r) part[mt][r] = fmaf(qv, ka[ntp][mt][r], part[mt][r]);
                }
#pragma unroll
            for (int mt = 0; mt < 4; ++mt)
#pragma unroll
                for (int r = 0; r < 4; ++r) {
#pragma unroll
                    for (int m = 1; m <= 8; m <<= 1) part[mt][r] += __shfl_xor(part[mt][r], m, 64);
                }
            if (cidx == 0) {
#pragma unroll
                for (int mt = 0; mt < 4; ++mt) {
                    float4 t = {part[mt][0], part[mt][1], part[mt][2], part[mt][3]};
                    *(float4*)&s_at[(4 * mt + quad) * 16 + 4 * h] = t;
                }
            }
        }
        __syncthreads();

        // ---- softmax (wave 0 only; lane = p*4+h) ----
        if (wv == 0) {
            int p = lane >> 2, h = lane & 3;
            float4 sc = *(float4*)&s_at[p * 16 + 4 * h];
            int pw = wu0 + p;
            float sim[4] = {sc.x, sc.y, sc.z, sc.w};
#pragma unroll
            for (int r = 0; r < 4; ++r) {
                int rxv = min((pw >> 1) + (r & 1), WD_ - 1);
                float cd = ((r >> 1) ? dyv1 : dyv0) - (float)abs(pw - 2 * rxv);
                sim[r] = sim[r] * 0.17677669529663687f + slopes[h] * cd;
            }
            float mx = fmaxf(fmaxf(sim[0], sim[1]), fmaxf(sim[2], sim[3]));
            float e0 = __expf(sim[0] - mx), e1 = __expf(sim[1] - mx);
            float e2 = __expf(sim[2] - mx), e3 = __expf(sim[3] - mx);
            float si = 1.f / (e0 + e1 + e2 + e3);
            float4 at = {e0 * si, e1 * si, e2 * si, e3 * si};
            *(float4*)&s_at[p * 16 + 4 * h] = at;
        }
        __syncthreads();

        // ---- v GEMM (nt half) + fused o = attn@v -> oT in slot0 (q is dead) ----
#pragma unroll 1
        for (int ntl = 0; ntl < 4; ++ntl) {
            int nt_g = 4 * wv + ntl;
            f4v va[4];
            float vbb = vb[ly * C_ + 16 * nt_g + cidx];
#pragma unroll
            for (int mt = 0; mt < 4; ++mt) { f4v t = {vbb, vbb, vbb, vbb}; va[mt] = t; }
#pragma unroll
            for (int kt = 0; kt < 4; ++kt) {
                s8v acn[4];
#pragma unroll
                for (int mt = 0; mt < 4; ++mt)
                    acn[mt] = *(const s8v*)(arena + (1 + mt) * SLOT + cidx * 136 + kt * 32 + 8 * quad);
                s8v w = *(const s8v*)(Wv + ((size_t)((kt * 8 + nt_g) * 64 + lane)) * 8);
#pragma unroll
                for (int mt = 0; mt < 4; ++mt)
                    va[mt] = __builtin_amdgcn_mfma_f32_16x16x32_bf16(acn[mt], w, va[mt], 0, 0, 0);
            }
            int h = nt_g >> 1;
#pragma unroll
            for (int mt = 0; mt < 4; ++mt) {
                float4 at = *(float4*)&s_at[(4 * mt + quad) * 16 + 4 * h];
                float ov = at.x * va[mt][0] + at.y * va[mt][1] + at.z * va[mt][2] + at.w * va[mt][3];
                arena[(4 * mt + quad) * 136 + 16 * nt_g + cidx] = f2bf(ov);
            }
        }
        __syncthreads();

        // ---- x += o @ Wo + ob (nt half) ----
        {
            s8v a_o[4];
#pragma unroll
            for (int kt = 0; kt < 4; ++kt)
                a_o[kt] = *(const s8v*)(arena + cidx * 136 + kt * 32 + 8 * quad);
            f4v oa[4];
#pragma unroll
            for (int ntl = 0; ntl < 4; ++ntl) {
                float bvv = ob[ly * C_ + 16 * (4 * wv + ntl) + cidx];
                f4v t = {bvv, bvv, bvv, bvv}; oa[ntl] = t;
            }
#pragma unroll
            for (int kt = 0; kt < 4; ++kt)
#pragma unroll
                for (int ntl = 0; ntl < 4; ++ntl) {
                    s8v w = *(const s8v*)(Wo + ((size_t)((kt * 8 + 4 * wv + ntl) * 64 + lane)) * 8);
                    oa[ntl] = __builtin_amdgcn_mfma_f32_16x16x32_bf16(a_o[kt], w, oa[ntl], 0, 0, 0);
                }
#pragma unroll
            for (int ntl = 0; ntl < 4; ++ntl)
#pragma unroll
                for (int r = 0; r < 4; ++r) xacc[ntl][r] += oa[ntl][r];
        }

        // ---- hn = LN(x,1e-6) -> slot0 (a_o reads complete before internal barrier) ----
        {
            float s[4], ss[4];
#pragma unroll
            for (int r = 0; r < 4; ++r) {
                s[r] = 0.f; ss[r] = 0.f;
#pragma unroll
                for (int ntl = 0; ntl < 4; ++ntl) { float v = xacc[ntl][r]; s[r] += v; ss[r] += v * v; }
#pragma unroll
                for (int m = 1; m <= 8; m <<= 1) { s[r] += __shfl_xor(s[r], m, 64); ss[r] += __shfl_xor(ss[r], m, 64); }
            }
            if (cidx == 0) {
#pragma unroll
                for (int r = 0; r < 4; ++r) {
                    int p = 4 * quad + r;
                    s_red[p * 2 + wv] = s[r];
                    s_red[64 + p * 2 + wv] = ss[r];
                }
            }
            __syncthreads();
            float mo[4], io[4];
#pragma unroll
            for (int r = 0; r < 4; ++r) {
                int p = 4 * quad + r;
                float st  = s_red[p * 2] + s_red[p * 2 + 1];
                float sst = s_red[64 + p * 2] + s_red[64 + p * 2 + 1];
                float mn = st * (1.f / 128.f);
                mo[r] = mn; io[r] = rsqrtf(sst * (1.f / 128.f) - mn * mn + 1e-6f);
            }
#pragma unroll
            for (int ntl = 0; ntl < 4; ++ntl)
#pragma unroll
                for (int r = 0; r < 4; ++r)
                    arena[(4 * quad + r) * 136 + 16 * (4 * wv + ntl) + cidx] =
                        f2bf((xacc[ntl][r] - mo[r]) * io[r]);
        }
        __syncthreads();
        s8v a_hn[4];
#pragma unroll
        for (int kt = 0; kt < 4; ++kt)
            a_hn[kt] = *(const s8v*)(arena + cidx * 136 + kt * 32 + 8 * quad);
        __syncthreads();

        // ---- fc1 (nt half: 16 tiles) + gelu_tanh -> sH (overlays slots 0-3) ----
        {
            f4v fa[16];
#pragma unroll
            for (int ntl = 0; ntl < 16; ++ntl) {
                float bvv = f1b[ly * 512 + 16 * (16 * wv + ntl) + cidx];
                f4v t = {bvv, bvv, bvv, bvv}; fa[ntl] = t;
            }
#pragma unroll
            for (int kt = 0; kt < 4; ++kt)
#pragma unroll
                for (int ntl = 0; ntl < 16; ++ntl) {
                    s8v w = *(const s8v*)(W1 + ((size_t)((kt * 32 + 16 * wv + ntl) * 64 + lane)) * 8);
                    fa[ntl] = __builtin_amdgcn_mfma_f32_16x16x32_bf16(a_hn[kt], w, fa[ntl], 0, 0, 0);
                }
#pragma unroll
            for (int ntl = 0; ntl < 16; ++ntl)
#pragma unroll
                for (int r = 0; r < 4; ++r)
                    sH[(4 * quad + r) * 520 + 16 * (16 * wv + ntl) + cidx] =
                        f2bf(gelu_tanh(fa[ntl][r]));
        }
        __syncthreads();

        // ---- x += act @ W2 + f2b (nt half) ----
        {
            f4v ga[4];
#pragma unroll
            for (int ntl = 0; ntl < 4; ++ntl) {
                float bvv = f2b[ly * C_ + 16 * (4 * wv + ntl) + cidx];
                f4v t = {bvv, bvv, bvv, bvv}; ga[ntl] = t;
            }
            for (int kt = 0; kt < 16; ++kt) {
                s8v a = *(const s8v*)(sH + cidx * 520 + kt * 32 + 8 * quad);
#pragma unroll
                for (int ntl = 0; ntl < 4; ++ntl) {
                    s8v w = *(const s8v*)(W2 + ((size_t)((kt * 8 + 4 * wv + ntl) * 64 + lane)) * 8);
                    ga[ntl] = __builtin_amdgcn_mfma_f32_16x16x32_bf16(a, w, ga[ntl], 0, 0, 0);
                }
            }
#pragma unroll
            for (int ntl = 0; ntl < 4; ++ntl)
#pragma unroll
                for (int r = 0; r < 4; ++r) xacc[ntl][r] += ga[ntl][r];
        }
        __syncthreads();
    } // layer loop

    // ================= head =================
    // xf = LN(x,1e-6) -> slot0
    {
        float s[4], ss[4];
#pragma unroll
        for (int r = 0; r < 4; ++r) {
            s[r] = 0.f; ss[r] = 0.f;
#pragma unroll
            for (int ntl = 0; ntl < 4; ++ntl) { float v = xacc[ntl][r]; s[r] += v; ss[r] += v * v; }
#pragma unroll
            for (int m = 1; m <= 8; m <<= 1) { s[r] += __shfl_xor(s[r], m, 64); ss[r] += __shfl_xor(ss[r], m, 64); }
        }
        if (cidx == 0) {
#pragma unroll
            for (int r = 0; r < 4; ++r) {
                int p = 4 * quad + r;
                s_red[p * 2 + wv] = s[r];
                s_red[64 + p * 2 + wv] = ss[r];
            }
        }
        __syncthreads();
        float mo[4], io[4];
#pragma unroll
        for (int r = 0; r < 4; ++r) {
            int p = 4 * quad + r;
            float st  = s_red[p * 2] + s_red[p * 2 + 1];
            float sst = s_red[64 + p * 2] + s_red[64 + p * 2 + 1];
            float mn = st * (1.f / 128.f);
            mo[r] = mn; io[r] = rsqrtf(sst * (1.f / 128.f) - mn * mn + 1e-6f);
        }
#pragma unroll
        for (int ntl = 0; ntl < 4; ++ntl)
#pragma unroll
            for (int r = 0; r < 4; ++r)
                arena[(4 * quad + r) * 136 + 16 * (4 * wv + ntl) + cidx] =
                    f2bf((xacc[ntl][r] - mo[r]) * io[r]);
    }
    // cf tiles (raw nrmb) -> slots 1-4 (this wave: mtg = 2wv, 2wv+1)
#pragma unroll
    for (int i = 0; i < 2; ++i) {
        int mtg = 2 * wv + i;
        const u16* csrc = nrmb + cbase[i] + 32 * quad;
        u16* drow = arena + (1 + mtg) * SLOT + cidx * 136 + 32 * quad;
#pragma unroll
        for (int t = 0; t < 4; ++t)
            *(s8v*)(drow + 8 * t) = *(const s8v*)(csrc + 8 * t);
    }
    __syncthreads();

    s8v a_xf[4];
#pragma unroll
    for (int kt = 0; kt < 4; ++kt)
        a_xf[kt] = *(const s8v*)(arena + cidx * 136 + kt * 32 + 8 * quad);

    const u16* Wxc = wsb + OFF_XC;
    const u16* Wcc = wsb + OFF_CC;
    float part[4][4];
#pragma unroll
    for (int mt = 0; mt < 4; ++mt)
#pragma unroll
        for (int r = 0; r < 4; ++r) part[mt][r] = 0.f;

#pragma unroll 1
    for (int ntc_l = 0; ntc_l < 2; ++ntc_l) {
        int ntc = 2 * wv + ntc_l;
#pragma unroll 1
        for (int half = 0; half < 2; ++half) {
            int nb = 6 * ntc + 3 * half;    // first n-tile of this group of 3
            // xf-part (with out1 bias folded in)
            f4v hx[3];
#pragma unroll
            for (int j = 0; j < 3; ++j) {
                float hb = o1b[16 * (nb + j) + cidx];
                f4v t = {hb, hb, hb, hb}; hx[j] = t;
            }
#pragma unroll
            for (int kt = 0; kt < 4; ++kt)
#pragma unroll
                for (int j = 0; j < 3; ++j) {
                    s8v w = *(const s8v*)(Wxc + ((size_t)((kt * 24 + nb + j) * 64 + lane)) * 8);
                    hx[j] = __builtin_amdgcn_mfma_f32_16x16x32_bf16(a_xf[kt], w, hx[j], 0, 0, 0);
                }
            // shuffle-transpose: lane(cidx,quad) wants hx value at row 4mt+quad, col cidx,
            // held by lane 16*mt+cidx, register r = quad
            float xfp[3][4];
#pragma unroll
            for (int j = 0; j < 3; ++j)
#pragma unroll
                for (int mt = 0; mt < 4; ++mt) {
                    int src = 16 * mt + cidx;
                    float t0 = __shfl(hx[j][0], src, 64);
                    float t1 = __shfl(hx[j][1], src, 64);
                    float t2 = __shfl(hx[j][2], src, 64);
                    float t3 = __shfl(hx[j][3], src, 64);
                    float a01 = (quad & 1) ? t1 : t0;
                    float a23 = (quad & 1) ? t3 : t2;
                    xfp[j][mt] = (quad & 2) ? a23 : a01;
                }
            // cf-part over all 4 M-tiles
            f4v hc[3][4];
#pragma unroll
            for (int j = 0; j < 3; ++j)
#pragma unroll
                for (int mt = 0; mt < 4; ++mt) { f4v t = {0.f, 0.f, 0.f, 0.f}; hc[j][mt] = t; }
#pragma unroll
            for (int kt = 0; kt < 4; ++kt) {
                s8v acf[4];
#pragma unroll
                for (int mt = 0; mt < 4; ++mt)
                    acf[mt] = *(const s8v*)(arena + (1 + mt) * SLOT + cidx * 136 + kt * 32 + 8 * quad);
#pragma unroll
                for (int j = 0; j < 3; ++j) {
                    s8v w = *(const s8v*)(Wcc + ((size_t)((kt * 24 + nb + j) * 64 + lane)) * 8);
#pragma unroll
                    for (int mt = 0; mt < 4; ++mt)
                        hc[j][mt] = __builtin_amdgcn_mfma_f32_16x16x32_bf16(acf[mt], w, hc[j][mt], 0, 0, 0);
                }
            }
            // h1 = gelu_erf(cf + xf); accumulate out2 dot
#pragma unroll
            for (int j = 0; j < 3; ++j) {
                float w2v = o2w[16 * (nb + j) + cidx];
#pragma unroll
                for (int mt = 0; mt < 4; ++mt)
#pragma unroll
                    for (int r = 0; r < 4; ++r)
                        part[mt][r] = fmaf(gelu_erf(hc[j][mt][r] + xfp[j][mt]), w2v, part[mt][r]);
            }
        }
    }

    // reduce over cidx, cross-wave via s_red, then softmax + store
#pragma unroll
    for (int mt = 0; mt < 4; ++mt)
#pragma unroll
        for (int r = 0; r < 4; ++r) {
#pragma unroll
            for (int m = 1; m <= 8; m <<= 1) part[mt][r] += __shfl_xor(part[mt][r], m, 64);
        }
    if (cidx == 0) {
#pragma unroll
        for (int mt = 0; mt < 4; ++mt)
#pragma unroll
            for (int r = 0; r < 4; ++r)
                s_red[(4 * mt + quad) * 8 + wv * 4 + r] = part[mt][r];
    }
    __syncthreads();

    if (tid < 16) {
        int p = tid;
        float o2bv = o2b[0];
        float v0 = s_red[p * 8 + 0] + s_red[p * 8 + 4] + o2bv;
        float v1 = s_red[p * 8 + 1] + s_red[p * 8 + 5] + o2bv;
        float v2 = s_red[p * 8 + 2] + s_red[p * 8 + 6] + o2bv;
        float v3 = s_red[p * 8 + 3] + s_red[p * 8 + 7] + o2bv;
        float mx = fmaxf(fmaxf(v0, v1), fmaxf(v2, v3));
        float e0 = __expf(v0 - mx), e1 = __expf(v1 - mx);
        float e2 = __expf(v2 - mx), e3 = __expf(v3 - mx);
        float si = 1.f / (e0 + e1 + e2 + e3);
        size_t base = ((size_t)(b * 4) * HU_ + hu) * WU_ + wu0 + p;
        out[base]                          = e0 * si;
        out[base + (size_t)HU_ * WU_]      = e1 * si;
        out[base + (size_t)2 * HU_ * WU_]  = e2 * si;
        out[base + (size_t)3 * HU_ * WU_]  = e3 * si;
    }
}

extern "C" void kernel_launch(void* const* d_in, const int* in_sizes, int n_in,
                              void* d_out, int out_size, void* d_ws, size_t ws_size,
                              hipStream_t stream) {
    const float* feat_map    = (const float*)d_in[0];
    const float* feat_map_up = (const float*)d_in[1];
    const float* ctx_ln_b    = (const float*)d_in[2];
    const float* q_w  = (const float*)d_in[3];
    const float* q_b  = (const float*)d_in[4];
    const float* k_w  = (const float*)d_in[5];
    const float* k_b  = (const float*)d_in[6];
    const float* v_w  = (const float*)d_in[7];
    const float* v_b  = (const float*)d_in[8];
    const float* o_w  = (const float*)d_in[9];
    const float* o_b  = (const float*)d_in[10];
    const float* fc1_w = (const float*)d_in[11];
    const float* fc1_b = (const float*)d_in[12];
    const float* fc2_w = (const float*)d_in[13];
    const float* fc2_b = (const float*)d_in[14];
    const float* out1_w = (const float*)d_in[15];
    const float* out1_b = (const float*)d_in[16];
    const float* out2_w = (const float*)d_in[17];
    const float* out2_b = (const float*)d_in[18];
    const float* ctx_ln_g = (const float*)d_in[19];
    float* out = (float*)d_out;
    u16* ws = (u16*)d_ws;

    swz_all<<<240, 256, 0, stream>>>(q_w, k_w, v_w, o_w, fc1_w, fc2_w, out1_w, ws);
    norm_kernel<<<128, 256, 0, stream>>>(feat_map, ws + OFF_NRM);

    fused_kernel<<<3072, 128, 0, stream>>>(
        ws + OFF_NRM, feat_map_up, ws, ctx_ln_g, ctx_ln_b,
        q_b, k_b, v_b, o_b, fc1_b, fc2_b,
        out1_b, out2_w, out2_b, out);
}

// Round 9
// 781.437 us; speedup vs baseline: 1.3781x; 1.3781x over previous
//
#include <hip/hip_runtime.h>
#include <math.h>

#define C_   128
#define HU_  128
#define WU_  192
#define HD_  64
#define WD_  96

typedef unsigned short u16;
typedef __attribute__((ext_vector_type(8))) short s8v;   // 8 bf16 = 4 VGPRs
typedef __attribute__((ext_vector_type(4))) float f4v;   // MFMA C/D

// ---- workspace layout (u16 units) ----
#define OFF_Q   0        // 2 layers x 16384
#define OFF_K   32768
#define OFF_V   65536
#define OFF_O   98304
#define OFF_F1  131072   // 2 layers x 65536
#define OFF_F2  262144
#define OFF_XC  393216   // 49152 (out1 Wa+Wc, 128x384)
#define OFF_CC  442368   // 49152 (out1 Wb-Wc, 128x384)
#define OFF_NRM 491520   // normalized ctx bf16: (B,HD,WD,C) = 1572864 u16

#define SLOT 2176        // u16 per LDS tile slot (16 rows x 136)

__device__ __forceinline__ u16 f2bf(float f) {
    unsigned u = __float_as_uint(f);
    unsigned r = (u + 0x7FFFu + ((u >> 16) & 1u)) >> 16;   // RNE
    return (u16)r;
}
__device__ __forceinline__ float bfu(u16 h) { return __uint_as_float(((unsigned)h) << 16); }

__device__ __forceinline__ float gelu_tanh(float x) {
    float u = 1.5957691216057308f * (x + 0.044715f * x * x * x);
    float e = __expf(u);
    float th = 1.0f - 2.0f / (1.0f + e);
    return 0.5f * x * (1.0f + th);
}
__device__ __forceinline__ float fast_erf(float x) {
    float z = fabsf(x);
    float t = 1.0f / (1.0f + 0.3275911f * z);
    float p = t * (0.254829592f + t * (-0.284496736f + t * (1.421413741f +
              t * (-1.453152027f + t * 1.061405429f))));
    float r = 1.0f - p * __expf(-z * z);
    return copysignf(r, x);
}
__device__ __forceinline__ float gelu_erf(float x) {
    return 0.5f * x * (1.0f + fast_erf(x * 0.7071067811865476f));
}

// ---------------- prologue 1: all weight swizzles (+ out1 folding) ----------------
__global__ __launch_bounds__(256) void swz_all(
    const float* __restrict__ q_w, const float* __restrict__ k_w,
    const float* __restrict__ v_w, const float* __restrict__ o_w,
    const float* __restrict__ f1w, const float* __restrict__ f2w,
    const float* __restrict__ o1w, u16* __restrict__ ws)
{
    int tid = blockIdx.x * 256 + threadIdx.x;
    int f = tid >> 6, lane = tid & 63;
    int rq = 8 * (lane >> 4), cq = lane & 15;
    const float* src; const float* src2 = nullptr; float sgn = 1.f;
    int NT, N, dstoff, lf;
    if (f < 64)       { src = q_w;  NT = 8;  N = 128; dstoff = OFF_Q;  lf = f; }
    else if (f < 128) { src = k_w;  NT = 8;  N = 128; dstoff = OFF_K;  lf = f - 64; }
    else if (f < 192) { src = v_w;  NT = 8;  N = 128; dstoff = OFF_V;  lf = f - 128; }
    else if (f < 256) { src = o_w;  NT = 8;  N = 128; dstoff = OFF_O;  lf = f - 192; }
    else if (f < 512) { src = f1w;  NT = 32; N = 512; dstoff = OFF_F1; lf = f - 256; }
    else if (f < 768) { src = f2w;  NT = 8;  N = 128; dstoff = OFF_F2; lf = f - 512; }
    else if (f < 864) { src = o1w;             src2 = o1w + 256 * 384; sgn =  1.f;
                        NT = 24; N = 384; dstoff = OFF_XC; lf = f - 768; }
    else              { src = o1w + 128 * 384; src2 = o1w + 256 * 384; sgn = -1.f;
                        NT = 24; N = 384; dstoff = OFF_CC; lf = f - 864; }
    int kt = lf / NT, nt = lf - kt * NT;
    int row0 = kt * 32 + rq, col = nt * 16 + cq;
    s8v o;
#pragma unroll
    for (int j = 0; j < 8; ++j) {
        float v = src[(size_t)(row0 + j) * N + col];
        if (src2) v += sgn * src2[(size_t)(row0 + j) * N + col];
        o[j] = (short)f2bf(v);
    }
    *(s8v*)(ws + dstoff + (size_t)lf * 512 + (size_t)lane * 8) = o;
}

// ---------------- prologue 2: per-down-pixel LN of feat_map (eps 1e-5) ----------------
__global__ __launch_bounds__(256) void norm_kernel(const float* __restrict__ fm,
                                                   u16* __restrict__ dst) {
    int row = blockIdx.x;          // b*HD + y
    int b = row >> 6, y = row & 63;
    __shared__ float tile[128 * 97];
    __shared__ float smean[96], srst[96];
    for (int idx = threadIdx.x; idx < 128 * 96; idx += 256) {
        int c = idx / 96, w = idx - c * 96;
        tile[c * 97 + w] = fm[(((size_t)b * 128 + c) * 64 + y) * 96 + w];
    }
    __syncthreads();
    if (threadIdx.x < 96) {
        int w = threadIdx.x;
        float s = 0.f, ss = 0.f;
        for (int c = 0; c < 128; ++c) { float v = tile[c * 97 + w]; s += v; ss += v * v; }
        float mn = s * (1.f / 128.f);
        smean[w] = mn;
        srst[w]  = rsqrtf(ss * (1.f / 128.f) - mn * mn + 1e-5f);
    }
    __syncthreads();
    for (int idx = threadIdx.x; idx < 96 * 16; idx += 256) {
        int w = idx >> 4, cg = idx & 15;
        float mn = smean[w], iv = srst[w];
        s8v o;
#pragma unroll
        for (int j = 0; j < 8; ++j)
            o[j] = (short)f2bf((tile[(8 * cg + j) * 97 + w] - mn) * iv);
        *(s8v*)(dst + ((size_t)row * 96 + w) * 128 + 8 * cg) = o;
    }
}

// ---------------- main fused kernel: 2 waves / block, 16 pixels / block ----------------
// Wave wv handles N-halves: nt_g = 4*wv..4*wv+3 (q/v/o/fc2), heads 2wv..2wv+1 (k),
// nt_g = 16wv.. (fc1), ntc chunks 2wv..2wv+1 (head). Shared LDS tiles, s_red for LN.
// launch_bounds(128,2): VGPR cap 256 -> no spills (r8's (128,3) forced an 84-reg
// allocation and 600+MB of scratch traffic).
__global__ __launch_bounds__(128, 2) void fused_kernel(
    const u16*  __restrict__ nrmb, const float* __restrict__ fmu,
    const u16*  __restrict__ wsb,
    const float* __restrict__ ctx_g, const float* __restrict__ ctx_b,
    const float* __restrict__ qb, const float* __restrict__ kb,
    const float* __restrict__ vb, const float* __restrict__ ob,
    const float* __restrict__ f1b, const float* __restrict__ f2b,
    const float* __restrict__ o1b, const float* __restrict__ o2w,
    const float* __restrict__ o2b,
    float* __restrict__ out)
{
    const int tid  = threadIdx.x;
    const int wv   = tid >> 6;
    const int lane = tid & 63;
    const int cidx = lane & 15, quad = lane >> 4;
    const int n0 = blockIdx.x * 16;
    const int b  = n0 / (HU_ * WU_);
    const int rem = n0 - b * (HU_ * WU_);
    const int hu  = rem / WU_;
    const int wu0 = rem - hu * WU_;

    __shared__ u16 arena[5 * SLOT];     // 21760 B: slot0 = xn/q/oT/hn/xf, slots1-4 = cn/cf; sH overlays 0-3
    __shared__ float s_at[272];
    __shared__ float s_red[128];
    u16* sH = arena;                    // fc1 acts, stride 520

    // residual x: wave wv owns channels 16*(4wv+ntl)+cidx, rows p = 4*quad+r
    float xacc[4][4];
#pragma unroll
    for (int ntl = 0; ntl < 4; ++ntl) {
        int ch = 16 * (4 * wv + ntl) + cidx;
        float4 v = *(const float4*)(fmu + ((size_t)(b * C_ + ch) * HU_ + hu) * WU_ + wu0 + 4 * quad);
        xacc[ntl][0] = v.x; xacc[ntl][1] = v.y; xacc[ntl][2] = v.z; xacc[ntl][3] = v.w;
    }

    const float slopes[4] = {0.451801007f, 0.204124145f, 0.092223264f, 0.041666668f};
    const int ry0 = min(hu >> 1, HD_ - 1);
    const int ry1 = min((hu >> 1) + 1, HD_ - 1);
    const float dyv0 = -(float)abs(hu - 2 * ry0);
    const float dyv1 = -(float)abs(hu - 2 * ry1);

    // ctx row base for the two tiles this wave builds (mtg = 2wv+i); tile row cidx = (p,k2)
    const int k2l = cidx & 3;
    const int ryl = (k2l >> 1) ? ry1 : ry0;
    int cbase[2];
#pragma unroll
    for (int i = 0; i < 2; ++i) {
        int mtg = 2 * wv + i;
        int p = 4 * mtg + (cidx >> 2);
        int rxv = min(((wu0 + p) >> 1) + (k2l & 1), WD_ - 1);
        cbase[i] = ((b * HD_ + ryl) * WD_ + rxv) * 128;
    }

#pragma unroll 1
    for (int ly = 0; ly < 2; ++ly) {
        const u16* Wq = wsb + OFF_Q  + ly * 16384;
        const u16* Wk = wsb + OFF_K  + ly * 16384;
        const u16* Wv = wsb + OFF_V  + ly * 16384;
        const u16* Wo = wsb + OFF_O  + ly * 16384;
        const u16* W1 = wsb + OFF_F1 + ly * 65536;
        const u16* W2 = wsb + OFF_F2 + ly * 65536;
        const float* gv = ctx_g + ly * C_;
        const float* bv = ctx_b + ly * C_;

        // ---- xn = LN(x,1e-6), cross-wave stats -> slot0 ----
        {
            float s[4], ss[4];
#pragma unroll
            for (int r = 0; r < 4; ++r) {
                s[r] = 0.f; ss[r] = 0.f;
#pragma unroll
                for (int ntl = 0; ntl < 4; ++ntl) { float v = xacc[ntl][r]; s[r] += v; ss[r] += v * v; }
#pragma unroll
                for (int m = 1; m <= 8; m <<= 1) { s[r] += __shfl_xor(s[r], m, 64); ss[r] += __shfl_xor(ss[r], m, 64); }
            }
            if (cidx == 0) {
#pragma unroll
                for (int r = 0; r < 4; ++r) {
                    int p = 4 * quad + r;
                    s_red[p * 2 + wv] = s[r];
                    s_red[64 + p * 2 + wv] = ss[r];
                }
            }
            __syncthreads();
            float mo[4], io[4];
#pragma unroll
            for (int r = 0; r < 4; ++r) {
                int p = 4 * quad + r;
                float st  = s_red[p * 2] + s_red[p * 2 + 1];
                float sst = s_red[64 + p * 2] + s_red[64 + p * 2 + 1];
                float mn = st * (1.f / 128.f);
                mo[r] = mn; io[r] = rsqrtf(sst * (1.f / 128.f) - mn * mn + 1e-6f);
            }
#pragma unroll
            for (int ntl = 0; ntl < 4; ++ntl)
#pragma unroll
                for (int r = 0; r < 4; ++r)
                    arena[(4 * quad + r) * 136 + 16 * (4 * wv + ntl) + cidx] =
                        f2bf((xacc[ntl][r] - mo[r]) * io[r]);
        }

        // ---- build cn tiles (this wave: mtg = 2wv, 2wv+1) -> slots 1-4 ----
#pragma unroll
        for (int i = 0; i < 2; ++i) {
            int mtg = 2 * wv + i;
            const u16* csrc = nrmb + cbase[i] + 32 * quad;
            u16* drow = arena + (1 + mtg) * SLOT + cidx * 136 + 32 * quad;
#pragma unroll
            for (int t = 0; t < 4; ++t) {
                s8v raw = *(const s8v*)(csrc + 8 * t);
                float4 g0 = *(const float4*)&gv[32 * quad + 8 * t];
                float4 g1 = *(const float4*)&gv[32 * quad + 8 * t + 4];
                float4 b0 = *(const float4*)&bv[32 * quad + 8 * t];
                float4 b1 = *(const float4*)&bv[32 * quad + 8 * t + 4];
                s8v o;
                o[0] = (short)f2bf(fmaf(bfu((u16)raw[0]), g0.x, b0.x));
                o[1] = (short)f2bf(fmaf(bfu((u16)raw[1]), g0.y, b0.y));
                o[2] = (short)f2bf(fmaf(bfu((u16)raw[2]), g0.z, b0.z));
                o[3] = (short)f2bf(fmaf(bfu((u16)raw[3]), g0.w, b0.w));
                o[4] = (short)f2bf(fmaf(bfu((u16)raw[4]), g1.x, b1.x));
                o[5] = (short)f2bf(fmaf(bfu((u16)raw[5]), g1.y, b1.y));
                o[6] = (short)f2bf(fmaf(bfu((u16)raw[6]), g1.z, b1.z));
                o[7] = (short)f2bf(fmaf(bfu((u16)raw[7]), g1.w, b1.w));
                *(s8v*)(drow + 8 * t) = o;
            }
        }
        __syncthreads();

        // ---- q: read xn frags, barrier, GEMM (nt half), overwrite slot0 with q bf16 ----
        s8v a_xn[4];
#pragma unroll
        for (int kt = 0; kt < 4; ++kt)
            a_xn[kt] = *(const s8v*)(arena + cidx * 136 + kt * 32 + 8 * quad);
        __syncthreads();
        {
            f4v qa[4];
#pragma unroll
            for (int ntl = 0; ntl < 4; ++ntl) {
                float bvv = qb[ly * C_ + 16 * (4 * wv + ntl) + cidx];
                f4v t = {bvv, bvv, bvv, bvv}; qa[ntl] = t;
            }
#pragma unroll
            for (int kt = 0; kt < 4; ++kt)
#pragma unroll
                for (int ntl = 0; ntl < 4; ++ntl) {
                    s8v w = *(const s8v*)(Wq + ((size_t)((kt * 8 + 4 * wv + ntl) * 64 + lane)) * 8);
                    qa[ntl] = __builtin_amdgcn_mfma_f32_16x16x32_bf16(a_xn[kt], w, qa[ntl], 0, 0, 0);
                }
#pragma unroll
            for (int ntl = 0; ntl < 4; ++ntl)
#pragma unroll
                for (int r = 0; r < 4; ++r)
                    arena[(4 * quad + r) * 136 + 16 * (4 * wv + ntl) + cidx] = f2bf(qa[ntl][r]);
        }
        __syncthreads();

        // ---- k GEMM (this wave: heads 2wv, 2wv+1) + fused raw scores -> s_at ----
#pragma unroll 1
        for (int h_l = 0; h_l < 2; ++h_l) {
            int h = 2 * wv + h_l;
            f4v ka[2][4];
#pragma unroll
            for (int ntp = 0; ntp < 2; ++ntp) {
                float kbb = kb[ly * C_ + 16 * (2 * h + ntp) + cidx];
#pragma unroll
                for (int mt = 0; mt < 4; ++mt) { f4v t = {kbb, kbb, kbb, kbb}; ka[ntp][mt] = t; }
            }
#pragma unroll
            for (int kt = 0; kt < 4; ++kt) {
                s8v acn[4];
#pragma unroll
                for (int mt = 0; mt < 4; ++mt)
                    acn[mt] = *(const s8v*)(arena + (1 + mt) * SLOT + cidx * 136 + kt * 32 + 8 * quad);
#pragma unroll
                for (int ntp = 0; ntp < 2; ++ntp) {
                    s8v w = *(const s8v*)(Wk + ((size_t)((kt * 8 + 2 * h + ntp) * 64 + lane)) * 8);
#pragma unroll
                    for (int mt = 0; mt < 4; ++mt)
                        ka[ntp][mt] = __builtin_amdgcn_mfma_f32_16x16x32_bf16(acn[mt], w, ka[ntp][mt], 0, 0, 0);
                }
            }
            float part[4][4];
#pragma unroll
            for (int mt = 0; mt < 4; ++mt)
#pragma unroll
                for (int r = 0; r < 4; ++r) part[mt][r] = 0.f;
#pragma unroll
            for (int ntp = 0; ntp < 2; ++ntp)
#pragma unroll
                for (int mt = 0; mt < 4; ++mt) {
                    float qv = bfu(arena[(4 * mt + quad) * 136 + 16 * (2 * h + ntp) + cidx]);
#pragma unroll
                    for (int r = 0; r < 4; ++r) part[mt][r] = fmaf(qv, ka[ntp][mt][r], part[mt][r]);
                }
#pragma unroll
            for (int mt = 0; mt < 4; ++mt)
#pragma unroll
                for (int r = 0; r < 4; ++r) {
#pragma unroll
                    for (int m = 1; m <= 8; m <<= 1) part[mt][r] += __shfl_xor(part[mt][r], m, 64);
                }
            if (cidx == 0) {
#pragma unroll
                for (int mt = 0; mt < 4; ++mt) {
                    float4 t = {part[mt][0], part[mt][1], part[mt][2], part[mt][3]};
                    *(float4*)&s_at[(4 * mt + quad) * 16 + 4 * h] = t;
                }
            }
        }
        __syncthreads();

        // ---- softmax (wave 0 only; lane = p*4+h) ----
        if (wv == 0) {
            int p = lane >> 2, h = lane & 3;
            float4 sc = *(float4*)&s_at[p * 16 + 4 * h];
            int pw = wu0 + p;
            float sim[4] = {sc.x, sc.y, sc.z, sc.w};
#pragma unroll
            for (int r = 0; r < 4; ++r) {
                int rxv = min((pw >> 1) + (r & 1), WD_ - 1);
                float cd = ((r >> 1) ? dyv1 : dyv0) - (float)abs(pw - 2 * rxv);
                sim[r] = sim[r] * 0.17677669529663687f + slopes[h] * cd;
            }
            float mx = fmaxf(fmaxf(sim[0], sim[1]), fmaxf(sim[2], sim[3]));
            float e0 = __expf(sim[0] - mx), e1 = __expf(sim[1] - mx);
            float e2 = __expf(sim[2] - mx), e3 = __expf(sim[3] - mx);
            float si = 1.f / (e0 + e1 + e2 + e3);
            float4 at = {e0 * si, e1 * si, e2 * si, e3 * si};
            *(float4*)&s_at[p * 16 + 4 * h] = at;
        }
        __syncthreads();

        // ---- v GEMM (nt half) + fused o = attn@v -> oT in slot0 (q is dead) ----
#pragma unroll 1
        for (int ntl = 0; ntl < 4; ++ntl) {
            int nt_g = 4 * wv + ntl;
            f4v va[4];
            float vbb = vb[ly * C_ + 16 * nt_g + cidx];
#pragma unroll
            for (int mt = 0; mt < 4; ++mt) { f4v t = {vbb, vbb, vbb, vbb}; va[mt] = t; }
#pragma unroll
            for (int kt = 0; kt < 4; ++kt) {
                s8v acn[4];
#pragma unroll
                for (int mt = 0; mt < 4; ++mt)
                    acn[mt] = *(const s8v*)(arena + (1 + mt) * SLOT + cidx * 136 + kt * 32 + 8 * quad);
                s8v w = *(const s8v*)(Wv + ((size_t)((kt * 8 + nt_g) * 64 + lane)) * 8);
#pragma unroll
                for (int mt = 0; mt < 4; ++mt)
                    va[mt] = __builtin_amdgcn_mfma_f32_16x16x32_bf16(acn[mt], w, va[mt], 0, 0, 0);
            }
            int h = nt_g >> 1;
#pragma unroll
            for (int mt = 0; mt < 4; ++mt) {
                float4 at = *(float4*)&s_at[(4 * mt + quad) * 16 + 4 * h];
                float ov = at.x * va[mt][0] + at.y * va[mt][1] + at.z * va[mt][2] + at.w * va[mt][3];
                arena[(4 * mt + quad) * 136 + 16 * nt_g + cidx] = f2bf(ov);
            }
        }
        __syncthreads();

        // ---- x += o @ Wo + ob (nt half) ----
        {
            s8v a_o[4];
#pragma unroll
            for (int kt = 0; kt < 4; ++kt)
                a_o[kt] = *(const s8v*)(arena + cidx * 136 + kt * 32 + 8 * quad);
            f4v oa[4];
#pragma unroll
            for (int ntl = 0; ntl < 4; ++ntl) {
                float bvv = ob[ly * C_ + 16 * (4 * wv + ntl) + cidx];
                f4v t = {bvv, bvv, bvv, bvv}; oa[ntl] = t;
            }
#pragma unroll
            for (int kt = 0; kt < 4; ++kt)
#pragma unroll
                for (int ntl = 0; ntl < 4; ++ntl) {
                    s8v w = *(const s8v*)(Wo + ((size_t)((kt * 8 + 4 * wv + ntl) * 64 + lane)) * 8);
                    oa[ntl] = __builtin_amdgcn_mfma_f32_16x16x32_bf16(a_o[kt], w, oa[ntl], 0, 0, 0);
                }
#pragma unroll
            for (int ntl = 0; ntl < 4; ++ntl)
#pragma unroll
                for (int r = 0; r < 4; ++r) xacc[ntl][r] += oa[ntl][r];
        }

        // ---- hn = LN(x,1e-6) -> slot0 (a_o reads complete before internal barrier) ----
        {
            float s[4], ss[4];
#pragma unroll
            for (int r = 0; r < 4; ++r) {
                s[r] = 0.f; ss[r] = 0.f;
#pragma unroll
                for (int ntl = 0; ntl < 4; ++ntl) { float v = xacc[ntl][r]; s[r] += v; ss[r] += v * v; }
#pragma unroll
                for (int m = 1; m <= 8; m <<= 1) { s[r] += __shfl_xor(s[r], m, 64); ss[r] += __shfl_xor(ss[r], m, 64); }
            }
            if (cidx == 0) {
#pragma unroll
                for (int r = 0; r < 4; ++r) {
                    int p = 4 * quad + r;
                    s_red[p * 2 + wv] = s[r];
                    s_red[64 + p * 2 + wv] = ss[r];
                }
            }
            __syncthreads();
            float mo[4], io[4];
#pragma unroll
            for (int r = 0; r < 4; ++r) {
                int p = 4 * quad + r;
                float st  = s_red[p * 2] + s_red[p * 2 + 1];
                float sst = s_red[64 + p * 2] + s_red[64 + p * 2 + 1];
                float mn = st * (1.f / 128.f);
                mo[r] = mn; io[r] = rsqrtf(sst * (1.f / 128.f) - mn * mn + 1e-6f);
            }
#pragma unroll
            for (int ntl = 0; ntl < 4; ++ntl)
#pragma unroll
                for (int r = 0; r < 4; ++r)
                    arena[(4 * quad + r) * 136 + 16 * (4 * wv + ntl) + cidx] =
                        f2bf((xacc[ntl][r] - mo[r]) * io[r]);
        }
        __syncthreads();
        s8v a_hn[4];
#pragma unroll
        for (int kt = 0; kt < 4; ++kt)
            a_hn[kt] = *(const s8v*)(arena + cidx * 136 + kt * 32 + 8 * quad);
        __syncthreads();

        // ---- fc1 (nt half: 16 tiles, in 2 chunks of 8) + gelu_tanh -> sH ----
#pragma unroll 1
        for (int g = 0; g < 2; ++g) {
            f4v fa[8];
#pragma unroll
            for (int ntl = 0; ntl < 8; ++ntl) {
                float bvv = f1b[ly * 512 + 16 * (16 * wv + 8 * g + ntl) + cidx];
                f4v t = {bvv, bvv, bvv, bvv}; fa[ntl] = t;
            }
#pragma unroll
            for (int kt = 0; kt < 4; ++kt)
#pragma unroll
                for (int ntl = 0; ntl < 8; ++ntl) {
                    s8v w = *(const s8v*)(W1 + ((size_t)((kt * 32 + 16 * wv + 8 * g + ntl) * 64 + lane)) * 8);
                    fa[ntl] = __builtin_amdgcn_mfma_f32_16x16x32_bf16(a_hn[kt], w, fa[ntl], 0, 0, 0);
                }
#pragma unroll
            for (int ntl = 0; ntl < 8; ++ntl)
#pragma unroll
                for (int r = 0; r < 4; ++r)
                    sH[(4 * quad + r) * 520 + 16 * (16 * wv + 8 * g + ntl) + cidx] =
                        f2bf(gelu_tanh(fa[ntl][r]));
        }
        __syncthreads();

        // ---- x += act @ W2 + f2b (nt half) ----
        {
            f4v ga[4];
#pragma unroll
            for (int ntl = 0; ntl < 4; ++ntl) {
                float bvv = f2b[ly * C_ + 16 * (4 * wv + ntl) + cidx];
                f4v t = {bvv, bvv, bvv, bvv}; ga[ntl] = t;
            }
            for (int kt = 0; kt < 16; ++kt) {
                s8v a = *(const s8v*)(sH + cidx * 520 + kt * 32 + 8 * quad);
#pragma unroll
                for (int ntl = 0; ntl < 4; ++ntl) {
                    s8v w = *(const s8v*)(W2 + ((size_t)((kt * 8 + 4 * wv + ntl) * 64 + lane)) * 8);
                    ga[ntl] = __builtin_amdgcn_mfma_f32_16x16x32_bf16(a, w, ga[ntl], 0, 0, 0);
                }
            }
#pragma unroll
            for (int ntl = 0; ntl < 4; ++ntl)
#pragma unroll
                for (int r = 0; r < 4; ++r) xacc[ntl][r] += ga[ntl][r];
        }
        __syncthreads();
    } // layer loop

    // ================= head =================
    // xf = LN(x,1e-6) -> slot0
    {
        float s[4], ss[4];
#pragma unroll
        for (int r = 0; r < 4; ++r) {
            s[r] = 0.f; ss[r] = 0.f;
#pragma unroll
            for (int ntl = 0; ntl < 4; ++ntl) { float v = xacc[ntl][r]; s[r] += v; ss[r] += v * v; }
#pragma unroll
            for (int m = 1; m <= 8; m <<= 1) { s[r] += __shfl_xor(s[r], m, 64); ss[r] += __shfl_xor(ss[r], m, 64); }
        }
        if (cidx == 0) {
#pragma unroll
            for (int r = 0; r < 4; ++r) {
                int p = 4 * quad + r;
                s_red[p * 2 + wv] = s[r];
                s_red[64 + p * 2 + wv] = ss[r];
            }
        }
        __syncthreads();
        float mo[4], io[4];
#pragma unroll
        for (int r = 0; r < 4; ++r) {
            int p = 4 * quad + r;
            float st  = s_red[p * 2] + s_red[p * 2 + 1];
            float sst = s_red[64 + p * 2] + s_red[64 + p * 2 + 1];
            float mn = st * (1.f / 128.f);
            mo[r] = mn; io[r] = rsqrtf(sst * (1.f / 128.f) - mn * mn + 1e-6f);
        }
#pragma unroll
        for (int ntl = 0; ntl < 4; ++ntl)
#pragma unroll
            for (int r = 0; r < 4; ++r)
                arena[(4 * quad + r) * 136 + 16 * (4 * wv + ntl) + cidx] =
                    f2bf((xacc[ntl][r] - mo[r]) * io[r]);
    }
    // cf tiles (raw nrmb) -> slots 1-4 (this wave: mtg = 2wv, 2wv+1)
#pragma unroll
    for (int i = 0; i < 2; ++i) {
        int mtg = 2 * wv + i;
        const u16* csrc = nrmb + cbase[i] + 32 * quad;
        u16* drow = arena + (1 + mtg) * SLOT + cidx * 136 + 32 * quad;
#pragma unroll
        for (int t = 0; t < 4; ++t)
            *(s8v*)(drow + 8 * t) = *(const s8v*)(csrc + 8 * t);
    }
    __syncthreads();

    s8v a_xf[4];
#pragma unroll
    for (int kt = 0; kt < 4; ++kt)
        a_xf[kt] = *(const s8v*)(arena + cidx * 136 + kt * 32 + 8 * quad);

    const u16* Wxc = wsb + OFF_XC;
    const u16* Wcc = wsb + OFF_CC;
    float part[4][4];
#pragma unroll
    for (int mt = 0; mt < 4; ++mt)
#pragma unroll
        for (int r = 0; r < 4; ++r) part[mt][r] = 0.f;

#pragma unroll 1
    for (int ntc_l = 0; ntc_l < 2; ++ntc_l) {
        int ntc = 2 * wv + ntc_l;
#pragma unroll 1
        for (int half = 0; half < 2; ++half) {
            int nb = 6 * ntc + 3 * half;    // first n-tile of this group of 3
            // xf-part (with out1 bias folded in)
            f4v hx[3];
#pragma unroll
            for (int j = 0; j < 3; ++j) {
                float hb = o1b[16 * (nb + j) + cidx];
                f4v t = {hb, hb, hb, hb}; hx[j] = t;
            }
#pragma unroll
            for (int kt = 0; kt < 4; ++kt)
#pragma unroll
                for (int j = 0; j < 3; ++j) {
                    s8v w = *(const s8v*)(Wxc + ((size_t)((kt * 24 + nb + j) * 64 + lane)) * 8);
                    hx[j] = __builtin_amdgcn_mfma_f32_16x16x32_bf16(a_xf[kt], w, hx[j], 0, 0, 0);
                }
            // shuffle-transpose: lane(cidx,quad) wants hx value at row 4mt+quad, col cidx,
            // held by lane 16*mt+cidx, register r = quad
            float xfp[3][4];
#pragma unroll
            for (int j = 0; j < 3; ++j)
#pragma unroll
                for (int mt = 0; mt < 4; ++mt) {
                    int src = 16 * mt + cidx;
                    float t0 = __shfl(hx[j][0], src, 64);
                    float t1 = __shfl(hx[j][1], src, 64);
                    float t2 = __shfl(hx[j][2], src, 64);
                    float t3 = __shfl(hx[j][3], src, 64);
                    float a01 = (quad & 1) ? t1 : t0;
                    float a23 = (quad & 1) ? t3 : t2;
                    xfp[j][mt] = (quad & 2) ? a23 : a01;
                }
            // cf-part over all 4 M-tiles
            f4v hc[3][4];
#pragma unroll
            for (int j = 0; j < 3; ++j)
#pragma unroll
                for (int mt = 0; mt < 4; ++mt) { f4v t = {0.f, 0.f, 0.f, 0.f}; hc[j][mt] = t; }
#pragma unroll
            for (int kt = 0; kt < 4; ++kt) {
                s8v acf[4];
#pragma unroll
                for (int mt = 0; mt < 4; ++mt)
                    acf[mt] = *(const s8v*)(arena + (1 + mt) * SLOT + cidx * 136 + kt * 32 + 8 * quad);
#pragma unroll
                for (int j = 0; j < 3; ++j) {
                    s8v w = *(const s8v*)(Wcc + ((size_t)((kt * 24 + nb + j) * 64 + lane)) * 8);
#pragma unroll
                    for (int mt = 0; mt < 4; ++mt)
                        hc[j][mt] = __builtin_amdgcn_mfma_f32_16x16x32_bf16(acf[mt], w, hc[j][mt], 0, 0, 0);
                }
            }
            // h1 = gelu_erf(cf + xf); accumulate out2 dot
#pragma unroll
            for (int j = 0; j < 3; ++j) {
                float w2v = o2w[16 * (nb + j) + cidx];
#pragma unroll
                for (int mt = 0; mt < 4; ++mt)
#pragma unroll
                    for (int r = 0; r < 4; ++r)
                        part[mt][r] = fmaf(gelu_erf(hc[j][mt][r] + xfp[j][mt]), w2v, part[mt][r]);
            }
        }
    }

    // reduce over cidx, cross-wave via s_red, then softmax + store
#pragma unroll
    for (int mt = 0; mt < 4; ++mt)
#pragma unroll
        for (int r = 0; r < 4; ++r) {
#pragma unroll
            for (int m = 1; m <= 8; m <<= 1) part[mt][r] += __shfl_xor(part[mt][r], m, 64);
        }
    if (cidx == 0) {
#pragma unroll
        for (int mt = 0; mt < 4; ++mt)
#pragma unroll
            for (int r = 0; r < 4; ++r)
                s_red[(4 * mt + quad) * 8 + wv * 4 + r] = part[mt][r];
    }
    __syncthreads();

    if (tid < 16) {
        int p = tid;
        float o2bv = o2b[0];
        float v0 = s_red[p * 8 + 0] + s_red[p * 8 + 4] + o2bv;
        float v1 = s_red[p * 8 + 1] + s_red[p * 8 + 5] + o2bv;
        float v2 = s_red[p * 8 + 2] + s_red[p * 8 + 6] + o2bv;
        float v3 = s_red[p * 8 + 3] + s_red[p * 8 + 7] + o2bv;
        float mx = fmaxf(fmaxf(v0, v1), fmaxf(v2, v3));
        float e0 = __expf(v0 - mx), e1 = __expf(v1 - mx);
        float e2 = __expf(v2 - mx), e3 = __expf(v3 - mx);
        float si = 1.f / (e0 + e1 + e2 + e3);
        size_t base = ((size_t)(b * 4) * HU_ + hu) * WU_ + wu0 + p;
        out[base]                          = e0 * si;
        out[base + (size_t)HU_ * WU_]      = e1 * si;
        out[base + (size_t)2 * HU_ * WU_]  = e2 * si;
        out[base + (size_t)3 * HU_ * WU_]  = e3 * si;
    }
}

extern "C" void kernel_launch(void* const* d_in, const int* in_sizes, int n_in,
                              void* d_out, int out_size, void* d_ws, size_t ws_size,
                              hipStream_t stream) {
    const float* feat_map    = (const float*)d_in[0];
    const float* feat_map_up = (const float*)d_in[1];
    const float* ctx_ln_b    = (const float*)d_in[2];
    const float* q_w  = (const float*)d_in[3];
    const float* q_b  = (const float*)d_in[4];
    const float* k_w  = (const float*)d_in[5];
    const float* k_b  = (const float*)d_in[6];
    const float* v_w  = (const float*)d_in[7];
    const float* v_b  = (const float*)d_in[8];
    const float* o_w  = (const float*)d_in[9];
    const float* o_b  = (const float*)d_in[10];
    const float* fc1_w = (const float*)d_in[11];
    const float* fc1_b = (const float*)d_in[12];
    const float* fc2_w = (const float*)d_in[13];
    const float* fc2_b = (const float*)d_in[14];
    const float* out1_w = (const float*)d_in[15];
    const float* out1_b = (const float*)d_in[16];
    const float* out2_w = (const float*)d_in[17];
    const float* out2_b = (const float*)d_in[18];
    const float* ctx_ln_g = (const float*)d_in[19];
    float* out = (float*)d_out;
    u16* ws = (u16*)d_ws;

    swz_all<<<240, 256, 0, stream>>>(q_w, k_w, v_w, o_w, fc1_w, fc2_w, out1_w, ws);
    norm_kernel<<<128, 256, 0, stream>>>(feat_map, ws + OFF_NRM);

    fused_kernel<<<3072, 128, 0, stream>>>(
        ws + OFF_NRM, feat_map_up, ws, ctx_ln_g, ctx_ln_b,
        q_b, k_b, v_b, o_b, fc1_b, fc2_b,
        out1_b, out2_w, out2_b, out);
}

// Round 10
// 584.067 us; speedup vs baseline: 1.8438x; 1.3379x over previous
//
#include <hip/hip_runtime.h>
#include <math.h>

#define C_   128
#define HU_  128
#define WU_  192
#define HD_  64
#define WD_  96

typedef unsigned short u16;
typedef __attribute__((ext_vector_type(8))) short s8v;   // 8 bf16 = 4 VGPRs
typedef __attribute__((ext_vector_type(4))) float f4v;   // MFMA C/D

// ---- workspace layout (u16 units) ----
#define OFF_Q   0        // 2 layers x 16384
#define OFF_K   32768
#define OFF_V   65536
#define OFF_O   98304
#define OFF_F1  131072   // 2 layers x 65536
#define OFF_F2  262144
#define OFF_XC  393216   // 49152 (out1 Wa+Wc, 128x384)
#define OFF_CC  442368   // 49152 (out1 Wb-Wc, 128x384)
#define OFF_NRM 491520   // normalized ctx bf16: (B,HD,WD,C) = 1572864 u16

#define SLOT 2176        // u16 per LDS tile slot (16 rows x 136)

__device__ __forceinline__ u16 f2bf(float f) {
    unsigned u = __float_as_uint(f);
    unsigned r = (u + 0x7FFFu + ((u >> 16) & 1u)) >> 16;   // RNE
    return (u16)r;
}
__device__ __forceinline__ float bfu(u16 h) { return __uint_as_float(((unsigned)h) << 16); }

__device__ __forceinline__ float gelu_tanh(float x) {
    float u = 1.5957691216057308f * (x + 0.044715f * x * x * x);
    float e = __expf(u);
    float th = 1.0f - 2.0f / (1.0f + e);
    return 0.5f * x * (1.0f + th);
}
__device__ __forceinline__ float fast_erf(float x) {
    float z = fabsf(x);
    float t = 1.0f / (1.0f + 0.3275911f * z);
    float p = t * (0.254829592f + t * (-0.284496736f + t * (1.421413741f +
              t * (-1.453152027f + t * 1.061405429f))));
    float r = 1.0f - p * __expf(-z * z);
    return copysignf(r, x);
}
__device__ __forceinline__ float gelu_erf(float x) {
    return 0.5f * x * (1.0f + fast_erf(x * 0.7071067811865476f));
}

// ---------------- prologue 1: all weight swizzles (+ out1 folding) ----------------
__global__ __launch_bounds__(256) void swz_all(
    const float* __restrict__ q_w, const float* __restrict__ k_w,
    const float* __restrict__ v_w, const float* __restrict__ o_w,
    const float* __restrict__ f1w, const float* __restrict__ f2w,
    const float* __restrict__ o1w, u16* __restrict__ ws)
{
    int tid = blockIdx.x * 256 + threadIdx.x;
    int f = tid >> 6, lane = tid & 63;
    int rq = 8 * (lane >> 4), cq = lane & 15;
    const float* src; const float* src2 = nullptr; float sgn = 1.f;
    int NT, N, dstoff, lf;
    if (f < 64)       { src = q_w;  NT = 8;  N = 128; dstoff = OFF_Q;  lf = f; }
    else if (f < 128) { src = k_w;  NT = 8;  N = 128; dstoff = OFF_K;  lf = f - 64; }
    else if (f < 192) { src = v_w;  NT = 8;  N = 128; dstoff = OFF_V;  lf = f - 128; }
    else if (f < 256) { src = o_w;  NT = 8;  N = 128; dstoff = OFF_O;  lf = f - 192; }
    else if (f < 512) { src = f1w;  NT = 32; N = 512; dstoff = OFF_F1; lf = f - 256; }
    else if (f < 768) { src = f2w;  NT = 8;  N = 128; dstoff = OFF_F2; lf = f - 512; }
    else if (f < 864) { src = o1w;             src2 = o1w + 256 * 384; sgn =  1.f;
                        NT = 24; N = 384; dstoff = OFF_XC; lf = f - 768; }
    else              { src = o1w + 128 * 384; src2 = o1w + 256 * 384; sgn = -1.f;
                        NT = 24; N = 384; dstoff = OFF_CC; lf = f - 864; }
    int kt = lf / NT, nt = lf - kt * NT;
    int row0 = kt * 32 + rq, col = nt * 16 + cq;
    s8v o;
#pragma unroll
    for (int j = 0; j < 8; ++j) {
        float v = src[(size_t)(row0 + j) * N + col];
        if (src2) v += sgn * src2[(size_t)(row0 + j) * N + col];
        o[j] = (short)f2bf(v);
    }
    *(s8v*)(ws + dstoff + (size_t)lf * 512 + (size_t)lane * 8) = o;
}

// ---------------- prologue 2: per-down-pixel LN of feat_map (eps 1e-5) ----------------
__global__ __launch_bounds__(256) void norm_kernel(const float* __restrict__ fm,
                                                   u16* __restrict__ dst) {
    int row = blockIdx.x;          // b*HD + y
    int b = row >> 6, y = row & 63;
    __shared__ float tile[128 * 97];
    __shared__ float smean[96], srst[96];
    for (int idx = threadIdx.x; idx < 128 * 96; idx += 256) {
        int c = idx / 96, w = idx - c * 96;
        tile[c * 97 + w] = fm[(((size_t)b * 128 + c) * 64 + y) * 96 + w];
    }
    __syncthreads();
    if (threadIdx.x < 96) {
        int w = threadIdx.x;
        float s = 0.f, ss = 0.f;
        for (int c = 0; c < 128; ++c) { float v = tile[c * 97 + w]; s += v; ss += v * v; }
        float mn = s * (1.f / 128.f);
        smean[w] = mn;
        srst[w]  = rsqrtf(ss * (1.f / 128.f) - mn * mn + 1e-5f);
    }
    __syncthreads();
    for (int idx = threadIdx.x; idx < 96 * 16; idx += 256) {
        int w = idx >> 4, cg = idx & 15;
        float mn = smean[w], iv = srst[w];
        s8v o;
#pragma unroll
        for (int j = 0; j < 8; ++j)
            o[j] = (short)f2bf((tile[(8 * cg + j) * 97 + w] - mn) * iv);
        *(s8v*)(dst + ((size_t)row * 96 + w) * 128 + 8 * cg) = o;
    }
}

// ---------------- main fused kernel: 1 wave = 16 pixels, 3-slot LDS arena ----------------
// slot0 = xn/q/oT/hn/xf; slots1-2 = cn/cf pair; sH (stride 280) overlays slots 0-2.
// k-scores, v, and head process context in mt-pairs to fit 3 slots (14 KB -> 11 blocks/CU).
__global__ __launch_bounds__(64, 2) void fused_kernel(
    const u16*  __restrict__ nrmb, const float* __restrict__ fmu,
    const u16*  __restrict__ wsb,
    const float* __restrict__ ctx_g, const float* __restrict__ ctx_b,
    const float* __restrict__ qb, const float* __restrict__ kb,
    const float* __restrict__ vb, const float* __restrict__ ob,
    const float* __restrict__ f1b, const float* __restrict__ f2b,
    const float* __restrict__ o1b, const float* __restrict__ o2w,
    const float* __restrict__ o2b,
    float* __restrict__ out)
{
    const int lane = threadIdx.x;
    const int cidx = lane & 15, quad = lane >> 4;
    const int n0 = blockIdx.x * 16;
    const int b  = n0 / (HU_ * WU_);
    const int rem = n0 - b * (HU_ * WU_);
    const int hu  = rem / WU_;
    const int wu0 = rem - hu * WU_;

    __shared__ u16 arena[3 * SLOT];     // 13056 B
    __shared__ float s_at[272];         // 1088 B (scores/attn; tail reused for results)
    u16* sH = arena;                    // fc1 acts, stride 280 (4480 u16, fits 3 slots)

    // residual x: row p = 4*quad+r, ch = 16*nt+cidx
    float xacc[8][4];
#pragma unroll
    for (int nt = 0; nt < 8; ++nt) {
        int ch = 16 * nt + cidx;
        float4 v = *(const float4*)(fmu + ((size_t)(b * C_ + ch) * HU_ + hu) * WU_ + wu0 + 4 * quad);
        xacc[nt][0] = v.x; xacc[nt][1] = v.y; xacc[nt][2] = v.z; xacc[nt][3] = v.w;
    }

    const float slopes[4] = {0.451801007f, 0.204124145f, 0.092223264f, 0.041666668f};
    const int ry0 = min(hu >> 1, HD_ - 1);
    const int ry1 = min((hu >> 1) + 1, HD_ - 1);
    const float dyv0 = -(float)abs(hu - 2 * ry0);
    const float dyv1 = -(float)abs(hu - 2 * ry1);

    // ctx row base per mtg: tile row cidx = (p_local=cidx>>2, k2=cidx&3)
    const int k2l = cidx & 3;
    const int ryl = (k2l >> 1) ? ry1 : ry0;
    int cbase[4];
#pragma unroll
    for (int mt = 0; mt < 4; ++mt) {
        int p = 4 * mt + (cidx >> 2);
        int rxv = min(((wu0 + p) >> 1) + (k2l & 1), WD_ - 1);
        cbase[mt] = ((b * HD_ + ryl) * WD_ + rxv) * 128;
    }

#pragma unroll 1
    for (int ly = 0; ly < 2; ++ly) {
        const u16* Wq = wsb + OFF_Q  + ly * 16384;
        const u16* Wk = wsb + OFF_K  + ly * 16384;
        const u16* Wv = wsb + OFF_V  + ly * 16384;
        const u16* Wo = wsb + OFF_O  + ly * 16384;
        const u16* W1 = wsb + OFF_F1 + ly * 65536;
        const u16* W2 = wsb + OFF_F2 + ly * 65536;
        const float* gv = ctx_g + ly * C_;
        const float* bv = ctx_b + ly * C_;

        // ---- xn = LN(x,1e-6) -> slot0 ----
        {
            float mo[4], io[4];
#pragma unroll
            for (int r = 0; r < 4; ++r) {
                float s = 0.f, ss = 0.f;
#pragma unroll
                for (int nt = 0; nt < 8; ++nt) { float v = xacc[nt][r]; s += v; ss += v * v; }
#pragma unroll
                for (int m = 1; m <= 8; m <<= 1) { s += __shfl_xor(s, m, 64); ss += __shfl_xor(ss, m, 64); }
                float mn = s * (1.f / 128.f);
                mo[r] = mn; io[r] = rsqrtf(ss * (1.f / 128.f) - mn * mn + 1e-6f);
            }
#pragma unroll
            for (int nt = 0; nt < 8; ++nt)
#pragma unroll
                for (int r = 0; r < 4; ++r)
                    arena[(4 * quad + r) * 136 + 16 * nt + cidx] =
                        f2bf((xacc[nt][r] - mo[r]) * io[r]);
        }
        __syncthreads();
        s8v a_xn[4];
#pragma unroll
        for (int kt = 0; kt < 4; ++kt)
            a_xn[kt] = *(const s8v*)(arena + cidx * 136 + kt * 32 + 8 * quad);
        __syncthreads();

        // ---- q = xn @ Wq + qb -> slot0 bf16 (overwrites xn) ----
        {
            f4v qa[8];
#pragma unroll
            for (int nt = 0; nt < 8; ++nt) {
                float bvv = qb[ly * C_ + 16 * nt + cidx];
                f4v t = {bvv, bvv, bvv, bvv}; qa[nt] = t;
            }
#pragma unroll
            for (int kt = 0; kt < 4; ++kt)
#pragma unroll
                for (int nt = 0; nt < 8; ++nt) {
                    s8v w = *(const s8v*)(Wq + ((size_t)((kt * 8 + nt) * 64 + lane)) * 8);
                    qa[nt] = __builtin_amdgcn_mfma_f32_16x16x32_bf16(a_xn[kt], w, qa[nt], 0, 0, 0);
                }
#pragma unroll
            for (int nt = 0; nt < 8; ++nt)
#pragma unroll
                for (int r = 0; r < 4; ++r)
                    arena[(4 * quad + r) * 136 + 16 * nt + cidx] = f2bf(qa[nt][r]);
        }
        __syncthreads();

        // ---- k-scores in mt-pairs: build cn pair -> slots1,2; GEMM all heads; raw scores ----
#pragma unroll 1
        for (int pr = 0; pr < 2; ++pr) {
#pragma unroll
            for (int i = 0; i < 2; ++i) {
                int mtg = 2 * pr + i;
                const u16* csrc = nrmb + cbase[mtg] + 32 * quad;
                u16* drow = arena + (1 + i) * SLOT + cidx * 136 + 32 * quad;
#pragma unroll
                for (int t = 0; t < 4; ++t) {
                    s8v raw = *(const s8v*)(csrc + 8 * t);
                    float4 g0 = *(const float4*)&gv[32 * quad + 8 * t];
                    float4 g1 = *(const float4*)&gv[32 * quad + 8 * t + 4];
                    float4 b0 = *(const float4*)&bv[32 * quad + 8 * t];
                    float4 b1 = *(const float4*)&bv[32 * quad + 8 * t + 4];
                    s8v o;
                    o[0] = (short)f2bf(fmaf(bfu((u16)raw[0]), g0.x, b0.x));
                    o[1] = (short)f2bf(fmaf(bfu((u16)raw[1]), g0.y, b0.y));
                    o[2] = (short)f2bf(fmaf(bfu((u16)raw[2]), g0.z, b0.z));
                    o[3] = (short)f2bf(fmaf(bfu((u16)raw[3]), g0.w, b0.w));
                    o[4] = (short)f2bf(fmaf(bfu((u16)raw[4]), g1.x, b1.x));
                    o[5] = (short)f2bf(fmaf(bfu((u16)raw[5]), g1.y, b1.y));
                    o[6] = (short)f2bf(fmaf(bfu((u16)raw[6]), g1.z, b1.z));
                    o[7] = (short)f2bf(fmaf(bfu((u16)raw[7]), g1.w, b1.w));
                    *(s8v*)(drow + 8 * t) = o;
                }
            }
            __syncthreads();
            // preload this pair's A-frags (32 VGPRs)
            s8v acn[4][2];
#pragma unroll
            for (int kt = 0; kt < 4; ++kt)
#pragma unroll
                for (int i = 0; i < 2; ++i)
                    acn[kt][i] = *(const s8v*)(arena + (1 + i) * SLOT + cidx * 136 + kt * 32 + 8 * quad);
#pragma unroll 1
            for (int h = 0; h < 4; ++h) {
                f4v ka[2][2];
#pragma unroll
                for (int ntp = 0; ntp < 2; ++ntp) {
                    float kbb = kb[ly * C_ + 16 * (2 * h + ntp) + cidx];
#pragma unroll
                    for (int i = 0; i < 2; ++i) { f4v t = {kbb, kbb, kbb, kbb}; ka[ntp][i] = t; }
                }
#pragma unroll
                for (int kt = 0; kt < 4; ++kt)
#pragma unroll
                    for (int ntp = 0; ntp < 2; ++ntp) {
                        s8v w = *(const s8v*)(Wk + ((size_t)((kt * 8 + 2 * h + ntp) * 64 + lane)) * 8);
#pragma unroll
                        for (int i = 0; i < 2; ++i)
                            ka[ntp][i] = __builtin_amdgcn_mfma_f32_16x16x32_bf16(acn[kt][i], w, ka[ntp][i], 0, 0, 0);
                    }
                float part[2][4];
#pragma unroll
                for (int i = 0; i < 2; ++i)
#pragma unroll
                    for (int r = 0; r < 4; ++r) part[i][r] = 0.f;
#pragma unroll
                for (int ntp = 0; ntp < 2; ++ntp)
#pragma unroll
                    for (int i = 0; i < 2; ++i) {
                        float qv = bfu(arena[(4 * (2 * pr + i) + quad) * 136 + 16 * (2 * h + ntp) + cidx]);
#pragma unroll
                        for (int r = 0; r < 4; ++r) part[i][r] = fmaf(qv, ka[ntp][i][r], part[i][r]);
                    }
#pragma unroll
                for (int i = 0; i < 2; ++i)
#pragma unroll
                    for (int r = 0; r < 4; ++r) {
#pragma unroll
                        for (int m = 1; m <= 8; m <<= 1) part[i][r] += __shfl_xor(part[i][r], m, 64);
                    }
                if (cidx == 0) {
#pragma unroll
                    for (int i = 0; i < 2; ++i) {
                        float4 t = {part[i][0], part[i][1], part[i][2], part[i][3]};
                        *(float4*)&s_at[(4 * (2 * pr + i) + quad) * 16 + 4 * h] = t;
                    }
                }
            }
            __syncthreads();
        }

        // ---- softmax in place (lane = p*4+h) ----
        {
            int p = lane >> 2, h = lane & 3;
            float4 sc = *(float4*)&s_at[p * 16 + 4 * h];
            int pw = wu0 + p;
            float sim[4] = {sc.x, sc.y, sc.z, sc.w};
#pragma unroll
            for (int r = 0; r < 4; ++r) {
                int rxv = min((pw >> 1) + (r & 1), WD_ - 1);
                float cd = ((r >> 1) ? dyv1 : dyv0) - (float)abs(pw - 2 * rxv);
                sim[r] = sim[r] * 0.17677669529663687f + slopes[h] * cd;
            }
            float mx = fmaxf(fmaxf(sim[0], sim[1]), fmaxf(sim[2], sim[3]));
            float e0 = __expf(sim[0] - mx), e1 = __expf(sim[1] - mx);
            float e2 = __expf(sim[2] - mx), e3 = __expf(sim[3] - mx);
            float si = 1.f / (e0 + e1 + e2 + e3);
            float4 at = {e0 * si, e1 * si, e2 * si, e3 * si};
            *(float4*)&s_at[p * 16 + 4 * h] = at;
        }
        __syncthreads();

        // ---- v GEMM in mt-pairs + fused o = attn@v -> oT rows in slot0 (q dead) ----
#pragma unroll 1
        for (int pr = 0; pr < 2; ++pr) {
#pragma unroll
            for (int i = 0; i < 2; ++i) {
                int mtg = 2 * pr + i;
                const u16* csrc = nrmb + cbase[mtg] + 32 * quad;
                u16* drow = arena + (1 + i) * SLOT + cidx * 136 + 32 * quad;
#pragma unroll
                for (int t = 0; t < 4; ++t) {
                    s8v raw = *(const s8v*)(csrc + 8 * t);
                    float4 g0 = *(const float4*)&gv[32 * quad + 8 * t];
                    float4 g1 = *(const float4*)&gv[32 * quad + 8 * t + 4];
                    float4 b0 = *(const float4*)&bv[32 * quad + 8 * t];
                    float4 b1 = *(const float4*)&bv[32 * quad + 8 * t + 4];
                    s8v o;
                    o[0] = (short)f2bf(fmaf(bfu((u16)raw[0]), g0.x, b0.x));
                    o[1] = (short)f2bf(fmaf(bfu((u16)raw[1]), g0.y, b0.y));
                    o[2] = (short)f2bf(fmaf(bfu((u16)raw[2]), g0.z, b0.z));
                    o[3] = (short)f2bf(fmaf(bfu((u16)raw[3]), g0.w, b0.w));
                    o[4] = (short)f2bf(fmaf(bfu((u16)raw[4]), g1.x, b1.x));
                    o[5] = (short)f2bf(fmaf(bfu((u16)raw[5]), g1.y, b1.y));
                    o[6] = (short)f2bf(fmaf(bfu((u16)raw[6]), g1.z, b1.z));
                    o[7] = (short)f2bf(fmaf(bfu((u16)raw[7]), g1.w, b1.w));
                    *(s8v*)(drow + 8 * t) = o;
                }
            }
            __syncthreads();
            s8v acn[4][2];
#pragma unroll
            for (int kt = 0; kt < 4; ++kt)
#pragma unroll
                for (int i = 0; i < 2; ++i)
                    acn[kt][i] = *(const s8v*)(arena + (1 + i) * SLOT + cidx * 136 + kt * 32 + 8 * quad);
#pragma unroll 1
            for (int nt = 0; nt < 8; ++nt) {
                f4v va[2];
                float vbb = vb[ly * C_ + 16 * nt + cidx];
#pragma unroll
                for (int i = 0; i < 2; ++i) { f4v t = {vbb, vbb, vbb, vbb}; va[i] = t; }
#pragma unroll
                for (int kt = 0; kt < 4; ++kt) {
                    s8v w = *(const s8v*)(Wv + ((size_t)((kt * 8 + nt) * 64 + lane)) * 8);
#pragma unroll
                    for (int i = 0; i < 2; ++i)
                        va[i] = __builtin_amdgcn_mfma_f32_16x16x32_bf16(acn[kt][i], w, va[i], 0, 0, 0);
                }
                int h = nt >> 1;
#pragma unroll
                for (int i = 0; i < 2; ++i) {
                    int p = 4 * (2 * pr + i) + quad;
                    float4 at = *(float4*)&s_at[p * 16 + 4 * h];
                    float ov = at.x * va[i][0] + at.y * va[i][1] + at.z * va[i][2] + at.w * va[i][3];
                    arena[p * 136 + 16 * nt + cidx] = f2bf(ov);
                }
            }
            __syncthreads();
        }

        // ---- x += o @ Wo + ob ----
        {
            s8v a_o[4];
#pragma unroll
            for (int kt = 0; kt < 4; ++kt)
                a_o[kt] = *(const s8v*)(arena + cidx * 136 + kt * 32 + 8 * quad);
            f4v oa[8];
#pragma unroll
            for (int nt = 0; nt < 8; ++nt) {
                float bvv = ob[ly * C_ + 16 * nt + cidx];
                f4v t = {bvv, bvv, bvv, bvv}; oa[nt] = t;
            }
#pragma unroll
            for (int kt = 0; kt < 4; ++kt)
#pragma unroll
                for (int nt = 0; nt < 8; ++nt) {
                    s8v w = *(const s8v*)(Wo + ((size_t)((kt * 8 + nt) * 64 + lane)) * 8);
                    oa[nt] = __builtin_amdgcn_mfma_f32_16x16x32_bf16(a_o[kt], w, oa[nt], 0, 0, 0);
                }
#pragma unroll
            for (int nt = 0; nt < 8; ++nt)
#pragma unroll
                for (int r = 0; r < 4; ++r) xacc[nt][r] += oa[nt][r];
        }
        __syncthreads();

        // ---- hn = LN(x,1e-6) -> slot0 ----
        {
            float mo[4], io[4];
#pragma unroll
            for (int r = 0; r < 4; ++r) {
                float s = 0.f, ss = 0.f;
#pragma unroll
                for (int nt = 0; nt < 8; ++nt) { float v = xacc[nt][r]; s += v; ss += v * v; }
#pragma unroll
                for (int m = 1; m <= 8; m <<= 1) { s += __shfl_xor(s, m, 64); ss += __shfl_xor(ss, m, 64); }
                float mn = s * (1.f / 128.f);
                mo[r] = mn; io[r] = rsqrtf(ss * (1.f / 128.f) - mn * mn + 1e-6f);
            }
#pragma unroll
            for (int nt = 0; nt < 8; ++nt)
#pragma unroll
                for (int r = 0; r < 4; ++r)
                    arena[(4 * quad + r) * 136 + 16 * nt + cidx] =
                        f2bf((xacc[nt][r] - mo[r]) * io[r]);
        }
        __syncthreads();
        s8v a_hn[4];
#pragma unroll
        for (int kt = 0; kt < 4; ++kt)
            a_hn[kt] = *(const s8v*)(arena + cidx * 136 + kt * 32 + 8 * quad);
        __syncthreads();

        // ---- MLP in two 256-col chunks: fc1 -> sH (stride 280), fc2 partial ----
        f4v ga[8];
#pragma unroll
        for (int nt = 0; nt < 8; ++nt) {
            float bvv = f2b[ly * C_ + 16 * nt + cidx];
            f4v t = {bvv, bvv, bvv, bvv}; ga[nt] = t;
        }
#pragma unroll 1
        for (int chk = 0; chk < 2; ++chk) {
#pragma unroll 1
            for (int g = 0; g < 2; ++g) {
                f4v fa[8];
#pragma unroll
                for (int ntl = 0; ntl < 8; ++ntl) {
                    int lnt = 8 * g + ntl;
                    float bvv = f1b[ly * 512 + 16 * (16 * chk + lnt) + cidx];
                    f4v t = {bvv, bvv, bvv, bvv}; fa[ntl] = t;
                }
#pragma unroll
                for (int kt = 0; kt < 4; ++kt)
#pragma unroll
                    for (int ntl = 0; ntl < 8; ++ntl) {
                        int ntg = 16 * chk + 8 * g + ntl;
                        s8v w = *(const s8v*)(W1 + ((size_t)((kt * 32 + ntg) * 64 + lane)) * 8);
                        fa[ntl] = __builtin_amdgcn_mfma_f32_16x16x32_bf16(a_hn[kt], w, fa[ntl], 0, 0, 0);
                    }
#pragma unroll
                for (int ntl = 0; ntl < 8; ++ntl)
#pragma unroll
                    for (int r = 0; r < 4; ++r)
                        sH[(4 * quad + r) * 280 + 16 * (8 * g + ntl) + cidx] =
                            f2bf(gelu_tanh(fa[ntl][r]));
            }
            __syncthreads();
            for (int ktl = 0; ktl < 8; ++ktl) {
                int kt = 8 * chk + ktl;
                s8v a = *(const s8v*)(sH + cidx * 280 + ktl * 32 + 8 * quad);
#pragma unroll
                for (int nt = 0; nt < 8; ++nt) {
                    s8v w = *(const s8v*)(W2 + ((size_t)((kt * 8 + nt) * 64 + lane)) * 8);
                    ga[nt] = __builtin_amdgcn_mfma_f32_16x16x32_bf16(a, w, ga[nt], 0, 0, 0);
                }
            }
            __syncthreads();
        }
#pragma unroll
        for (int nt = 0; nt < 8; ++nt)
#pragma unroll
            for (int r = 0; r < 4; ++r) xacc[nt][r] += ga[nt][r];
    } // layer loop

    // ================= head =================
    // xf = LN(x,1e-6) -> slot0, preload a_xf
    {
        float mo[4], io[4];
#pragma unroll
        for (int r = 0; r < 4; ++r) {
            float s = 0.f, ss = 0.f;
#pragma unroll
            for (int nt = 0; nt < 8; ++nt) { float v = xacc[nt][r]; s += v; ss += v * v; }
#pragma unroll
            for (int m = 1; m <= 8; m <<= 1) { s += __shfl_xor(s, m, 64); ss += __shfl_xor(ss, m, 64); }
            float mn = s * (1.f / 128.f);
            mo[r] = mn; io[r] = rsqrtf(ss * (1.f / 128.f) - mn * mn + 1e-6f);
        }
#pragma unroll
        for (int nt = 0; nt < 8; ++nt)
#pragma unroll
            for (int r = 0; r < 4; ++r)
                arena[(4 * quad + r) * 136 + 16 * nt + cidx] =
                    f2bf((xacc[nt][r] - mo[r]) * io[r]);
    }
    __syncthreads();
    s8v a_xf[4];
#pragma unroll
    for (int kt = 0; kt < 4; ++kt)
        a_xf[kt] = *(const s8v*)(arena + cidx * 136 + kt * 32 + 8 * quad);

    const u16* Wxc = wsb + OFF_XC;
    const u16* Wcc = wsb + OFF_CC;

#pragma unroll 1
    for (int pr = 0; pr < 2; ++pr) {
        // cf pair tiles (raw nrmb) -> slots1,2
#pragma unroll
        for (int i = 0; i < 2; ++i) {
            int mtg = 2 * pr + i;
            const u16* csrc = nrmb + cbase[mtg] + 32 * quad;
            u16* drow = arena + (1 + i) * SLOT + cidx * 136 + 32 * quad;
#pragma unroll
            for (int t = 0; t < 4; ++t)
                *(s8v*)(drow + 8 * t) = *(const s8v*)(csrc + 8 * t);
        }
        __syncthreads();
        s8v acf[4][2];
#pragma unroll
        for (int kt = 0; kt < 4; ++kt)
#pragma unroll
            for (int i = 0; i < 2; ++i)
                acf[kt][i] = *(const s8v*)(arena + (1 + i) * SLOT + cidx * 136 + kt * 32 + 8 * quad);

        float part[2][4];
#pragma unroll
        for (int i = 0; i < 2; ++i)
#pragma unroll
            for (int r = 0; r < 4; ++r) part[i][r] = 0.f;

#pragma unroll 1
        for (int ntc = 0; ntc < 4; ++ntc) {
#pragma unroll 1
            for (int g = 0; g < 2; ++g) {
                int nb = 6 * ntc + 3 * g;
                // xf-part (with out1 bias folded)
                f4v hx[3];
#pragma unroll
                for (int j = 0; j < 3; ++j) {
                    float hb = o1b[16 * (nb + j) + cidx];
                    f4v t = {hb, hb, hb, hb}; hx[j] = t;
                }
#pragma unroll
                for (int kt = 0; kt < 4; ++kt)
#pragma unroll
                    for (int j = 0; j < 3; ++j) {
                        s8v w = *(const s8v*)(Wxc + ((size_t)((kt * 24 + nb + j) * 64 + lane)) * 8);
                        hx[j] = __builtin_amdgcn_mfma_f32_16x16x32_bf16(a_xf[kt], w, hx[j], 0, 0, 0);
                    }
                // shuffle-transpose: value for pixel P=4*(2pr+i)+quad, col cidx lives at
                // lane 16*(2pr+i)+cidx, reg r=quad... (P>>2 = 2pr+i since quad<4)
                float xfp[3][2];
#pragma unroll
                for (int j = 0; j < 3; ++j)
#pragma unroll
                    for (int i = 0; i < 2; ++i) {
                        int src = 16 * (2 * pr + i) + cidx;
                        float t0 = __shfl(hx[j][0], src, 64);
                        float t1 = __shfl(hx[j][1], src, 64);
                        float t2 = __shfl(hx[j][2], src, 64);
                        float t3 = __shfl(hx[j][3], src, 64);
                        float a01 = (quad & 1) ? t1 : t0;
                        float a23 = (quad & 1) ? t3 : t2;
                        xfp[j][i] = (quad & 2) ? a23 : a01;
                    }
                // cf-part for the pair
                f4v hc[3][2];
#pragma unroll
                for (int j = 0; j < 3; ++j)
#pragma unroll
                    for (int i = 0; i < 2; ++i) { f4v t = {0.f, 0.f, 0.f, 0.f}; hc[j][i] = t; }
#pragma unroll
                for (int kt = 0; kt < 4; ++kt)
#pragma unroll
                    for (int j = 0; j < 3; ++j) {
                        s8v w = *(const s8v*)(Wcc + ((size_t)((kt * 24 + nb + j) * 64 + lane)) * 8);
#pragma unroll
                        for (int i = 0; i < 2; ++i)
                            hc[j][i] = __builtin_amdgcn_mfma_f32_16x16x32_bf16(acf[kt][i], w, hc[j][i], 0, 0, 0);
                    }
                // h1 = gelu_erf(cf + xf); out2 dot accumulate
#pragma unroll
                for (int j = 0; j < 3; ++j) {
                    float w2v = o2w[16 * (nb + j) + cidx];
#pragma unroll
                    for (int i = 0; i < 2; ++i)
#pragma unroll
                        for (int r = 0; r < 4; ++r)
                            part[i][r] = fmaf(gelu_erf(hc[j][i][r] + xfp[j][i]), w2v, part[i][r]);
                }
            }
        }
        // reduce over cidx, store per-pixel results into s_at tail
#pragma unroll
        for (int i = 0; i < 2; ++i)
#pragma unroll
            for (int r = 0; r < 4; ++r) {
#pragma unroll
                for (int m = 1; m <= 8; m <<= 1) part[i][r] += __shfl_xor(part[i][r], m, 64);
            }
        if (cidx == 0) {
#pragma unroll
            for (int i = 0; i < 2; ++i) {
                int p = 4 * (2 * pr + i) + quad;
                float4 t = {part[i][0], part[i][1], part[i][2], part[i][3]};
                *(float4*)&s_at[192 + p * 4] = t;
            }
        }
        __syncthreads();
    }

    // final softmax over K2 + store
    if (lane < 16) {
        int p = lane;
        float o2bv = o2b[0];
        float4 vv = *(float4*)&s_at[192 + 4 * p];
        float v0 = vv.x + o2bv, v1 = vv.y + o2bv, v2 = vv.z + o2bv, v3 = vv.w + o2bv;
        float mx = fmaxf(fmaxf(v0, v1), fmaxf(v2, v3));
        float e0 = __expf(v0 - mx), e1 = __expf(v1 - mx);
        float e2 = __expf(v2 - mx), e3 = __expf(v3 - mx);
        float si = 1.f / (e0 + e1 + e2 + e3);
        size_t base = ((size_t)(b * 4) * HU_ + hu) * WU_ + wu0 + p;
        out[base]                          = e0 * si;
        out[base + (size_t)HU_ * WU_]      = e1 * si;
        out[base + (size_t)2 * HU_ * WU_]  = e2 * si;
        out[base + (size_t)3 * HU_ * WU_]  = e3 * si;
    }
}

extern "C" void kernel_launch(void* const* d_in, const int* in_sizes, int n_in,
                              void* d_out, int out_size, void* d_ws, size_t ws_size,
                              hipStream_t stream) {
    const float* feat_map    = (const float*)d_in[0];
    const float* feat_map_up = (const float*)d_in[1];
    const float* ctx_ln_b    = (const float*)d_in[2];
    const float* q_w  = (const float*)d_in[3];
    const float* q_b  = (const float*)d_in[4];
    const float* k_w  = (const float*)d_in[5];
    const float* k_b  = (const float*)d_in[6];
    const float* v_w  = (const float*)d_in[7];
    const float* v_b  = (const float*)d_in[8];
    const float* o_w  = (const float*)d_in[9];
    const float* o_b  = (const float*)d_in[10];
    const float* fc1_w = (const float*)d_in[11];
    const float* fc1_b = (const float*)d_in[12];
    const float* fc2_w = (const float*)d_in[13];
    const float* fc2_b = (const float*)d_in[14];
    const float* out1_w = (const float*)d_in[15];
    const float* out1_b = (const float*)d_in[16];
    const float* out2_w = (const float*)d_in[17];
    const float* out2_b = (const float*)d_in[18];
    const float* ctx_ln_g = (const float*)d_in[19];
    float* out = (float*)d_out;
    u16* ws = (u16*)d_ws;

    swz_all<<<240, 256, 0, stream>>>(q_w, k_w, v_w, o_w, fc1_w, fc2_w, out1_w, ws);
    norm_kernel<<<128, 256, 0, stream>>>(feat_map, ws + OFF_NRM);

    fused_kernel<<<3072, 64, 0, stream>>>(
        ws + OFF_NRM, feat_map_up, ws, ctx_ln_g, ctx_ln_b,
        q_b, k_b, v_b, o_b, fc1_b, fc2_b,
        out1_b, out2_w, out2_b, out);
}